// Round 8
// baseline (138.343 us; speedup 1.0000x reference)
//
#include <hip/hip_runtime.h>
#include <stdint.h>

// Problem constants: B=2, S=2048, D=1024, H=16, DH=64; M = B*S = 4096.

typedef __attribute__((ext_vector_type(8))) short s16x8;   // 8 bf16 (MFMA A/B frag)
typedef __attribute__((ext_vector_type(4))) float fx4;     // MFMA C/D frag
typedef __attribute__((ext_vector_type(4))) unsigned int ux4;
typedef __attribute__((ext_vector_type(2))) unsigned int ux2;

__device__ __forceinline__ unsigned short f2bf(float x) {
  unsigned u = __builtin_bit_cast(unsigned, x);
  u += 0x7fffu + ((u >> 16) & 1u);          // RNE
  return (unsigned short)(u >> 16);
}
__device__ __forceinline__ float bf2f(unsigned short h) {
  return __builtin_bit_cast(float, (unsigned)h << 16);
}

// async global->LDS, 16B per lane; LDS dest = wave-uniform base + lane*16
__device__ __forceinline__ void gload_lds16(const void* g, void* l) {
  __builtin_amdgcn_global_load_lds(
      (const __attribute__((address_space(1))) unsigned int*)g,
      (__attribute__((address_space(3))) unsigned int*)l, 16, 0, 0);
}

// ---------------- conversion: f32 -> bf16 ----------------
__global__ void k_conv_bf16(const float* __restrict__ X,
                            unsigned short* __restrict__ Y, int n4) {
  int stride = gridDim.x * blockDim.x;
  for (int i = blockIdx.x * blockDim.x + threadIdx.x; i < n4; i += stride) {
    fx4 v = *(const fx4*)(X + (size_t)i * 4);
    ux2 o;
    o[0] = (unsigned)f2bf(v[0]) | ((unsigned)f2bf(v[1]) << 16);
    o[1] = (unsigned)f2bf(v[2]) | ((unsigned)f2bf(v[3]) << 16);
    *(ux2*)(Y + (size_t)i * 4) = o;
  }
}

// ---------------- transpose + convert: W[k][n] f32 -> Wt[n][k] bf16 ----------------
__global__ void k_transpose_w(const float* __restrict__ W0, const float* __restrict__ W1,
                              const float* __restrict__ W2, const float* __restrict__ W3,
                              unsigned short* __restrict__ T0, unsigned short* __restrict__ T1,
                              unsigned short* __restrict__ T2, unsigned short* __restrict__ T3) {
  const float* W = blockIdx.z == 0 ? W0 : blockIdx.z == 1 ? W1 : blockIdx.z == 2 ? W2 : W3;
  unsigned short* T = blockIdx.z == 0 ? T0 : blockIdx.z == 1 ? T1 : blockIdx.z == 2 ? T2 : T3;
  __shared__ float t[32][33];
  int bx = blockIdx.x * 32, by = blockIdx.y * 32;
  int tx = threadIdx.x, ty = threadIdx.y;
#pragma unroll
  for (int i = 0; i < 32; i += 8)
    t[ty + i][tx] = W[(size_t)(by + ty + i) * 1024 + bx + tx];
  __syncthreads();
#pragma unroll
  for (int i = 0; i < 32; i += 8)
    T[(size_t)(bx + ty + i) * 1024 + by + tx] = f2bf(t[tx][ty + i]);
}

// ---------------- GEMM: C[M x Ntot] = A[M x 1024] * Wt ----
// tile 128x128, BK=64, 256 thr (4 waves 2x2 of 64x64), mfma 16x16x32 bf16.
// MODE 1: f32 C store. MODE 2: fused RMSNorm-over-64 + split to qn/kn/vb
// [32][2048][64] layout (q pre-scaled by 0.125*log2e).
template <int MODE>
__global__ __launch_bounds__(256, 2)
void k_gemm_bt(const unsigned short* __restrict__ A,
               const unsigned short* __restrict__ W0,
               const unsigned short* __restrict__ W1,
               const unsigned short* __restrict__ W2,
               void* __restrict__ Cptr, int ldc,
               unsigned short* __restrict__ qn, unsigned short* __restrict__ kn,
               unsigned short* __restrict__ vb) {
  __shared__ unsigned short As[128 * 64];
  __shared__ unsigned short Bs[128 * 64];
  const int tid = threadIdx.x;
  const int w = tid >> 6, l = tid & 63;
  const int lr = l & 15, lg = l >> 4;
  const int wm = w >> 1, wn = w & 1;
  const int m0 = blockIdx.x * 128;
  const int nt = blockIdx.y;
  const unsigned short* Bt = (nt < 8) ? W0 : (nt < 16) ? W1 : W2;
  const int n0 = (nt & 7) * 128;

  fx4 acc[4][4] = {};

  const int srow = w * 8 + (l >> 3);              // row within a 32-row issue block
  const int skb  = ((l & 7) ^ (l >> 3)) * 8;      // pre-swizzled 16B slot (elements)
  const unsigned short* aB = A  + (size_t)(m0 + srow) * 1024 + skb;
  const unsigned short* bB = Bt + (size_t)(n0 + srow) * 1024 + skb;
  unsigned short* aD = &As[w * 512];
  unsigned short* bD = &Bs[w * 512];
  const int rdswz = (l & 7) << 4;

  for (int kt = 0; kt < 1024; kt += 64) {
    __syncthreads();
#pragma unroll
    for (int j = 0; j < 4; ++j) {
      gload_lds16(aB + j * 32768 + kt, aD + j * 2048);
      gload_lds16(bB + j * 32768 + kt, bD + j * 2048);
    }
    __syncthreads();
#pragma unroll
    for (int ks = 0; ks < 2; ++ks) {
      const int kb = (ks * 64 + lg * 16) ^ rdswz;
      s16x8 af[4], bf[4];
#pragma unroll
      for (int mf = 0; mf < 4; ++mf)
        af[mf] = *(const s16x8*)((const char*)As + (wm * 64 + mf * 16 + lr) * 128 + kb);
#pragma unroll
      for (int nf = 0; nf < 4; ++nf)
        bf[nf] = *(const s16x8*)((const char*)Bs + (wn * 64 + nf * 16 + lr) * 128 + kb);
#pragma unroll
      for (int mf = 0; mf < 4; ++mf)
#pragma unroll
        for (int nf = 0; nf < 4; ++nf)
          acc[mf][nf] = __builtin_amdgcn_mfma_f32_16x16x32_bf16(af[mf], bf[nf], acc[mf][nf], 0, 0, 0);
    }
  }

  // C/D layout: row = (l>>4)*4 + reg, col = l&15
  if (MODE == 1) {
    const int gn = nt * 128 + wn * 64;
    const int gm = m0 + wm * 64;
#pragma unroll
    for (int mf = 0; mf < 4; ++mf)
#pragma unroll
      for (int r = 0; r < 4; ++r) {
        int row = gm + mf * 16 + lg * 4 + r;
        float* C = (float*)Cptr + (size_t)row * ldc + gn;
#pragma unroll
        for (int nf = 0; nf < 4; ++nf) C[nf * 16 + lr] = acc[mf][nf][r];
      }
  } else {
    // MODE 2: RMS over the wave's 64-col head block, write to [32][2048][64]
    const int tz = nt >> 3;                       // 0=q 1=k 2=v
    const int h  = ((nt & 7) << 1) | wn;
    const int gm = m0 + wm * 64;
    unsigned short* base = tz == 0 ? qn : tz == 1 ? kn : vb;
    const float cmul = (tz == 0) ? 0.18033688f : 1.0f;   // 0.125 * log2(e)
#pragma unroll
    for (int mf = 0; mf < 4; ++mf)
#pragma unroll
      for (int r = 0; r < 4; ++r) {
        int m = gm + mf * 16 + lg * 4 + r;
        float ss = 0.f;
#pragma unroll
        for (int nf = 0; nf < 4; ++nf) ss += acc[mf][nf][r] * acc[mf][nf][r];
        ss += __shfl_xor(ss, 1);
        ss += __shfl_xor(ss, 2);
        ss += __shfl_xor(ss, 4);
        ss += __shfl_xor(ss, 8);
        float scale = (tz == 2) ? 1.0f : rsqrtf(ss * (1.0f / 64.0f) + 1e-6f) * cmul;
        int b = m >> 11, s = m & 2047;
        unsigned short* dst = base + ((size_t)(((b << 4) + h) * 2048 + s)) * 64;
#pragma unroll
        for (int nf = 0; nf < 4; ++nf)
          dst[nf * 16 + lr] = f2bf(acc[mf][nf][r] * scale);
      }
  }
}

// ---------------- flash attention (causal), split-K, uniform blocks, PIPELINED ----
// Structure identical to R6 (grid 1024 = bh*32 + p*2+half; chunk A 17 steps incl.
// tile-p direct write, chunk B 16 steps; fixed softmax max; partials merge by add).
// 2-stage software pipeline per iteration:
//   issue K(t+2) gload -> QK^T(t+1) into scN -> writeV(t+1) regs->LDS ->
//   loadV(t+2) into regs -> softmax(t)+PV(t) from scP -> barrier.
// R7 BUG FIX: writeV(t+1) must consume the V registers BEFORE loadV(t+2)
// clobbers them (R7 wrote V(t+2) into the V(t+1) slot -> V shifted by one tile).
// Hazard audit: Vt[(t+1)&1] last read by smPV(t-1), complete before body(t-1)'s
// barrier -> early write safe. K(t+2)->Ks[t&1] safe (K(t) dead since QK(t) in
// body(t-1)). One barrier per iteration.
__global__ __launch_bounds__(128, 2)
void k_attn(const unsigned short* __restrict__ Q,   // [32][2048][64], pre-scaled
            const unsigned short* __restrict__ K,
            const unsigned short* __restrict__ V,
            unsigned short* __restrict__ O,         // [2][2048][1024]
            float* __restrict__ pO,                 // [32*16][2][64][64]
            float* __restrict__ pL) {               // [32*16][2][64]
  __shared__ unsigned short Ks[2][64 * 64];     // [kv][dh] swizzled, 8KB each
  __shared__ unsigned short Vt[2][64 * 64];     // [dh][kv'] swizzled, 8KB each
  __shared__ unsigned short Ps[2][32 * 64];     // per-wave P [row][kv'] swizzled, 4KB

  const int id = blockIdx.x;
  const int bh = id >> 5;
  const int c  = id & 31;
  const int p  = c >> 1, half = c & 1;
  const int tid = threadIdx.x;
  const int w = tid >> 6, l = tid & 63;
  const int lr = l & 15, lg = l >> 4;
  const int b = bh >> 4, h = bh & 15;

  const unsigned short* Kb = K + (size_t)bh * 2048 * 64;
  const unsigned short* Vb = V + (size_t)bh * 2048 * 64;
  const unsigned short* Qh = Q + (size_t)bh * 2048 * 64;

  const int ksub = l >> 3;                      // row-within-8 for K staging
  const int kskb = ((l & 7) ^ ksub) * 8;        // pre-swizzled 16B slot (elements)
  const int vc = tid & 31;                      // u32 column (kv' pair index)
  const int vg = tid >> 5;                      // 0..3 dh quarter
  const int kvlo = (vc & 15) + (vc >> 4) * 32;  // kv rows kvlo, kvlo+16
  const int rdswz = (lr & 7) << 4;
  const float FMAX = 11.5415603f;               // 8 * log2(e)

  const int NS = half ? 16 : 17;                // steps for this chunk (min 16)
  int tile = half ? (31 - p) : p;
  int qw = tile * 64 + w * 32;

  // stream geometry: step s -> KV tile index
  auto kvtOf = [&](int s) -> int {
    if (half) return 16 - p + s;
    return (s <= p) ? s : (s - p - 1);
  };

  s16x8 aq[2][2];
  auto loadAQ = [&]() {
#pragma unroll
    for (int mf = 0; mf < 2; ++mf)
#pragma unroll
      for (int ks = 0; ks < 2; ++ks)
        aq[mf][ks] = *(const s16x8*)(Qh + (size_t)(qw + mf * 16 + lr) * 64 + ks * 32 + lg * 8);
  };
  loadAQ();

  fx4 oacc[2][4] = {};
  float lsum[2][4] = {{0.f, 0.f, 0.f, 0.f}, {0.f, 0.f, 0.f, 0.f}};

  auto issueK = [&](int s, int buf) {
    const int kv0 = kvtOf(s) * 64;
#pragma unroll
    for (int j = 0; j < 4; ++j)
      gload_lds16(Kb + (size_t)(kv0 + j * 16 + w * 8 + ksub) * 64 + kskb,
                  &Ks[buf][(j * 16 + w * 8) * 64]);
  };
  ux4 va0, va1, va2, va3;
  auto loadV = [&](int s) {
    const int kv0 = kvtOf(s) * 64;
    va0 = *(const ux4*)(Vb + (size_t)(kv0 + kvlo) * 64 + vg * 16);
    va1 = *(const ux4*)(Vb + (size_t)(kv0 + kvlo) * 64 + vg * 16 + 8);
    va2 = *(const ux4*)(Vb + (size_t)(kv0 + kvlo + 16) * 64 + vg * 16);
    va3 = *(const ux4*)(Vb + (size_t)(kv0 + kvlo + 16) * 64 + vg * 16 + 8);
  };
  auto writeV = [&](int buf) {
    union { ux4 v; unsigned short u[8]; } a0, a1, a2, a3;
    a0.v = va0; a1.v = va1; a2.v = va2; a3.v = va3;
#pragma unroll
    for (int i = 0; i < 8; ++i) {
      int dh = vg * 16 + i;
      *(unsigned*)((char*)&Vt[buf][0] + dh * 128 + ((vc * 4) ^ ((i & 7) << 4))) =
          (unsigned)a0.u[i] | ((unsigned)a2.u[i] << 16);
      *(unsigned*)((char*)&Vt[buf][0] + (dh + 8) * 128 + ((vc * 4) ^ ((i & 7) << 4))) =
          (unsigned)a1.u[i] | ((unsigned)a3.u[i] << 16);
    }
  };
  auto qk = [&](fx4 (&sc)[2][4], int buf) {
#pragma unroll
    for (int mf = 0; mf < 2; ++mf)
#pragma unroll
      for (int nf = 0; nf < 4; ++nf) sc[mf][nf] = fx4{0.f, 0.f, 0.f, 0.f};
    __builtin_amdgcn_s_setprio(1);
#pragma unroll
    for (int ks = 0; ks < 2; ++ks) {
      const int kb = (ks * 64 + lg * 16) ^ rdswz;
#pragma unroll
      for (int nf = 0; nf < 4; ++nf) {
        s16x8 bk = *(const s16x8*)((const char*)&Ks[buf][0] + (nf * 16 + lr) * 128 + kb);
#pragma unroll
        for (int mf = 0; mf < 2; ++mf)
          sc[mf][nf] = __builtin_amdgcn_mfma_f32_16x16x32_bf16(aq[mf][ks], bk, sc[mf][nf], 0, 0, 0);
      }
    }
    __builtin_amdgcn_s_setprio(0);
  };
  auto maskDiag = [&](fx4 (&sc)[2][4], int kv0) {
#pragma unroll
    for (int mf = 0; mf < 2; ++mf)
#pragma unroll
      for (int nf = 0; nf < 4; ++nf)
#pragma unroll
        for (int r = 0; r < 4; ++r) {
          int gq = qw + mf * 16 + lg * 4 + r;
          int gk = kv0 + nf * 16 + lr;
          if (gk > gq) sc[mf][nf][r] = -3.0e38f;
        }
  };
  auto smPV = [&](fx4 (&sc)[2][4], int vbuf) {
    char* pw = (char*)&Ps[w][0];
#pragma unroll
    for (int mf = 0; mf < 2; ++mf)
#pragma unroll
      for (int r = 0; r < 4; ++r) {
        float e0 = __builtin_amdgcn_exp2f(sc[mf][0][r] - FMAX);
        float e1 = __builtin_amdgcn_exp2f(sc[mf][1][r] - FMAX);
        float e2 = __builtin_amdgcn_exp2f(sc[mf][2][r] - FMAX);
        float e3 = __builtin_amdgcn_exp2f(sc[mf][3][r] - FMAX);
        lsum[mf][r] += (e0 + e1) + (e2 + e3);
        unsigned u01, u23;
        asm("v_cvt_pk_bf16_f32 %0, %1, %2" : "=v"(u01) : "v"(e0), "v"(e1));
        asm("v_cvt_pk_bf16_f32 %0, %1, %2" : "=v"(u23) : "v"(e2), "v"(e3));
        int row = mf * 16 + lg * 4 + r;
        char* pb = pw + row * 128;
        int swz = (row & 7) << 4;
        *(unsigned*)(pb + ((4 * lr) ^ swz)) = u01;
        *(unsigned*)(pb + ((64 + 4 * lr) ^ swz)) = u23;
      }
    __builtin_amdgcn_s_setprio(1);
#pragma unroll
    for (int ks = 0; ks < 2; ++ks) {
      s16x8 pa[2], bv[4];
#pragma unroll
      for (int mf = 0; mf < 2; ++mf) {
        int row = mf * 16 + lr;
        pa[mf] = *(const s16x8*)(pw + row * 128 + ((ks * 64 + lg * 16) ^ ((row & 7) << 4)));
      }
#pragma unroll
      for (int nf = 0; nf < 4; ++nf) {
        int row = nf * 16 + lr;
        bv[nf] = *(const s16x8*)((const char*)&Vt[vbuf][0] + row * 128 +
                                 ((ks * 64 + lg * 16) ^ ((row & 7) << 4)));
      }
#pragma unroll
      for (int mf = 0; mf < 2; ++mf)
#pragma unroll
        for (int nf = 0; nf < 4; ++nf)
          oacc[mf][nf] = __builtin_amdgcn_mfma_f32_16x16x32_bf16(pa[mf], bv[nf], oacc[mf][nf], 0, 0, 0);
    }
    __builtin_amdgcn_s_setprio(0);
  };

  // ---- prologue: stage steps 0 and 1; compute QK(0) ----
  issueK(0, 0);
  issueK(1, 1);
  loadV(0);
  writeV(0);
  loadV(1);                       // held in regs; written during iter 0
  __syncthreads();                // drains K gloads; V0 visible

  fx4 scA[2][4], scB[2][4];
  qk(scA, 0);
  if (!half && p == 0) maskDiag(scA, 0);   // step 0 is tile 0's diagonal only if p==0

  // ---- pipelined body (scP = step t, scN = step t+1) ----
  auto body = [&](fx4 (&scP)[2][4], fx4 (&scN)[2][4], int t) {
    const bool hasN1 = (t + 1 < NS);
    const bool hasN2 = (t + 2 < NS);
    if (hasN2) issueK(t + 2, t & 1);            // K(t) dead since B_{t-1}
    if (hasN1) {
      if (!half && (t + 1 == p + 1)) {          // tile switch for QK(t+1)
        tile = 31 - p;
        qw = tile * 64 + w * 32;
        loadAQ();
      }
      qk(scN, (t + 1) & 1);
      if ((!half && t + 1 == p) || (half && t + 1 == 15))
        maskDiag(scN, kvtOf(t + 1) * 64);       // qw matches tile(t+1) here
    }
    // FIX: consume V(t+1) from regs BEFORE loadV(t+2) clobbers them.
    if (hasN1) writeV((t + 1) & 1);             // V(t+1) regs -> LDS
    if (hasN2) loadV(t + 2);
    smPV(scP, t & 1);
    if (!half && t == p) {
      // direct epilogue for tile p (complete); uses tile-p geometry explicitly
#pragma unroll
      for (int mf = 0; mf < 2; ++mf)
#pragma unroll
        for (int r = 0; r < 4; ++r) {
          float ssum = lsum[mf][r];
          ssum += __shfl_xor(ssum, 1);
          ssum += __shfl_xor(ssum, 2);
          ssum += __shfl_xor(ssum, 4);
          ssum += __shfl_xor(ssum, 8);
          float inv = 1.0f / ssum;
          int gq = p * 64 + w * 32 + mf * 16 + lg * 4 + r;
          unsigned short* orow = O + ((size_t)(b * 2048 + gq)) * 1024 + h * 64;
#pragma unroll
          for (int nf = 0; nf < 4; ++nf)
            orow[nf * 16 + lr] = f2bf(oacc[mf][nf][r] * inv);
        }
      // reset AFTER all outputs written (R5 lesson)
#pragma unroll
      for (int mf = 0; mf < 2; ++mf) {
#pragma unroll
        for (int nf = 0; nf < 4; ++nf) oacc[mf][nf] = fx4{0.f, 0.f, 0.f, 0.f};
#pragma unroll
        for (int r = 0; r < 4; ++r) lsum[mf][r] = 0.f;
      }
    }
    __syncthreads();
  };

#pragma unroll 1
  for (int t = 0; t < NS; t += 2) {
    body(scA, scB, t);
    if (t + 1 < NS) body(scB, scA, t + 1);
  }

  // final epilogue: write f32 partials for tile 31-p
  const int slot = ((bh * 16 + p) * 2 + half);
#pragma unroll
  for (int mf = 0; mf < 2; ++mf)
#pragma unroll
    for (int r = 0; r < 4; ++r) {
      float ssum = lsum[mf][r];
      ssum += __shfl_xor(ssum, 1);
      ssum += __shfl_xor(ssum, 2);
      ssum += __shfl_xor(ssum, 4);
      ssum += __shfl_xor(ssum, 8);
      int row = w * 32 + mf * 16 + lg * 4 + r;  // 0..63 within tile
      float* po = pO + ((size_t)slot * 64 + row) * 64;
#pragma unroll
      for (int nf = 0; nf < 4; ++nf) po[nf * 16 + lr] = oacc[mf][nf][r];
      if (lr == 0) pL[slot * 64 + row] = ssum;
    }
}

// ---------------- merge split-K partials for tiles 16..31 ----------------
__global__ __launch_bounds__(256)
void k_merge(const float* __restrict__ pO, const float* __restrict__ pL,
             unsigned short* __restrict__ O) {
  int gid = blockIdx.x * 256 + threadIdx.x;     // 524288 = 32768 rows x 16 quads
  int row = gid >> 4;                           // (bh*16 + p)*64 + r
  int quad = gid & 15;
  int slot = row >> 6;                          // bh*16 + p
  int r = row & 63;
  int bh = slot >> 4, p = slot & 15;
  fx4 va = *(const fx4*)(pO + ((size_t)(slot * 2) * 64 + r) * 64 + quad * 4);
  fx4 vb = *(const fx4*)(pO + ((size_t)(slot * 2 + 1) * 64 + r) * 64 + quad * 4);
  float inv = 1.0f / (pL[(slot * 2) * 64 + r] + pL[(slot * 2 + 1) * 64 + r]);
  int tile = 31 - p;
  int b = bh >> 4, h = bh & 15;
  int s = tile * 64 + r;
  unsigned short* o = O + ((size_t)(b * 2048 + s)) * 1024 + h * 64 + quad * 4;
  ux2 out;
  out[0] = (unsigned)f2bf((va[0] + vb[0]) * inv) | ((unsigned)f2bf((va[1] + vb[1]) * inv) << 16);
  out[1] = (unsigned)f2bf((va[2] + vb[2]) * inv) | ((unsigned)f2bf((va[3] + vb[3]) * inv) << 16);
  *(ux2*)o = out;
}

// ---------------- launch ----------------
extern "C" void kernel_launch(void* const* d_in, const int* in_sizes, int n_in,
                              void* d_out, int out_size, void* d_ws, size_t ws_size,
                              hipStream_t stream) {
  const float* x  = (const float*)d_in[0];
  const float* Wq = (const float*)d_in[1];
  const float* Wk = (const float*)d_in[2];
  const float* Wv = (const float*)d_in[3];
  const float* Wo = (const float*)d_in[4];
  // d_in[5] = causal mask (tril) — implemented analytically.

  char* ws = (char*)d_ws;                                  // ~65 MB
  unsigned short* xb   = (unsigned short*)(ws);            // 8 MB  [4096][1024]
  unsigned short* WqT  = (unsigned short*)(ws + (8ll  << 20));
  unsigned short* WkT  = (unsigned short*)(ws + (10ll << 20));
  unsigned short* WvT  = (unsigned short*)(ws + (12ll << 20));
  unsigned short* WoT  = (unsigned short*)(ws + (14ll << 20));
  unsigned short* qn   = (unsigned short*)(ws + (16ll << 20)); // 8 MB [32][2048][64]
  unsigned short* kn   = (unsigned short*)(ws + (24ll << 20));
  unsigned short* vb   = (unsigned short*)(ws + (32ll << 20));
  unsigned short* attn = (unsigned short*)(ws + (40ll << 20)); // 8 MB [4096][1024]
  float* pO            = (float*)(ws + (48ll << 20));          // 16 MB
  float* pL            = (float*)(ws + (64ll << 20));          // 256 KB

  k_conv_bf16<<<1024, 256, 0, stream>>>(x, xb, 4096 * 1024 / 4);
  k_transpose_w<<<dim3(32, 32, 4), dim3(32, 8), 0, stream>>>(Wq, Wk, Wv, Wo, WqT, WkT, WvT, WoT);
  k_gemm_bt<2><<<dim3(32, 24), 256, 0, stream>>>(xb, WqT, WkT, WvT, nullptr, 0, qn, kn, vb);
  k_attn<<<1024, 128, 0, stream>>>(qn, kn, vb, attn, pO, pL);
  k_merge<<<2048, 256, 0, stream>>>(pO, pL, attn);
  k_gemm_bt<1><<<dim3(32, 8), 256, 0, stream>>>(attn, WoT, WoT, WoT, d_out, 1024, nullptr, nullptr, nullptr);
}

// Round 9
// 110.478 us; speedup vs baseline: 1.2522x; 1.2522x over previous
//
#include <hip/hip_runtime.h>
#include <stdint.h>

// Problem constants: B=2, S=2048, D=1024, H=16, DH=64; M = B*S = 4096.

typedef __attribute__((ext_vector_type(8))) short s16x8;   // 8 bf16 (MFMA A/B frag)
typedef __attribute__((ext_vector_type(4))) float fx4;     // MFMA C/D frag
typedef __attribute__((ext_vector_type(4))) unsigned int ux4;
typedef __attribute__((ext_vector_type(2))) unsigned int ux2;

__device__ __forceinline__ unsigned short f2bf(float x) {
  unsigned u = __builtin_bit_cast(unsigned, x);
  u += 0x7fffu + ((u >> 16) & 1u);          // RNE
  return (unsigned short)(u >> 16);
}
__device__ __forceinline__ float bf2f(unsigned short h) {
  return __builtin_bit_cast(float, (unsigned)h << 16);
}

// async global->LDS, 16B per lane; LDS dest = wave-uniform base + lane*16
__device__ __forceinline__ void gload_lds16(const void* g, void* l) {
  __builtin_amdgcn_global_load_lds(
      (const __attribute__((address_space(1))) unsigned int*)g,
      (__attribute__((address_space(3))) unsigned int*)l, 16, 0, 0);
}

// ---------------- conversion: f32 -> bf16 ----------------
__global__ void k_conv_bf16(const float* __restrict__ X,
                            unsigned short* __restrict__ Y, int n4) {
  int stride = gridDim.x * blockDim.x;
  for (int i = blockIdx.x * blockDim.x + threadIdx.x; i < n4; i += stride) {
    fx4 v = *(const fx4*)(X + (size_t)i * 4);
    ux2 o;
    o[0] = (unsigned)f2bf(v[0]) | ((unsigned)f2bf(v[1]) << 16);
    o[1] = (unsigned)f2bf(v[2]) | ((unsigned)f2bf(v[3]) << 16);
    *(ux2*)(Y + (size_t)i * 4) = o;
  }
}

// ---------------- transpose + convert: W[k][n] f32 -> Wt[n][k] bf16 ----------------
__global__ void k_transpose_w(const float* __restrict__ W0, const float* __restrict__ W1,
                              const float* __restrict__ W2, const float* __restrict__ W3,
                              unsigned short* __restrict__ T0, unsigned short* __restrict__ T1,
                              unsigned short* __restrict__ T2, unsigned short* __restrict__ T3) {
  const float* W = blockIdx.z == 0 ? W0 : blockIdx.z == 1 ? W1 : blockIdx.z == 2 ? W2 : W3;
  unsigned short* T = blockIdx.z == 0 ? T0 : blockIdx.z == 1 ? T1 : blockIdx.z == 2 ? T2 : T3;
  __shared__ float t[32][33];
  int bx = blockIdx.x * 32, by = blockIdx.y * 32;
  int tx = threadIdx.x, ty = threadIdx.y;
#pragma unroll
  for (int i = 0; i < 32; i += 8)
    t[ty + i][tx] = W[(size_t)(by + ty + i) * 1024 + bx + tx];
  __syncthreads();
#pragma unroll
  for (int i = 0; i < 32; i += 8)
    T[(size_t)(bx + ty + i) * 1024 + by + tx] = f2bf(t[tx][ty + i]);
}

// ---------------- GEMM: C[M x Ntot] = A[M x 1024] * Wt ----
// tile 128x128, BK=64, 256 thr (4 waves 2x2 of 64x64), mfma 16x16x32 bf16.
// launch_bounds(256,3): cap VGPR ~170 so 3 blocks/CU co-reside (m97-class fit 164).
// MODE 1: f32 C store. MODE 2: fused RMSNorm-over-64 + split to qn/kn/vb.
template <int MODE>
__global__ __launch_bounds__(256, 3)
void k_gemm_bt(const unsigned short* __restrict__ A,
               const unsigned short* __restrict__ W0,
               const unsigned short* __restrict__ W1,
               const unsigned short* __restrict__ W2,
               void* __restrict__ Cptr, int ldc,
               unsigned short* __restrict__ qn, unsigned short* __restrict__ kn,
               unsigned short* __restrict__ vb) {
  __shared__ unsigned short As[128 * 64];
  __shared__ unsigned short Bs[128 * 64];
  const int tid = threadIdx.x;
  const int w = tid >> 6, l = tid & 63;
  const int lr = l & 15, lg = l >> 4;
  const int wm = w >> 1, wn = w & 1;
  const int m0 = blockIdx.x * 128;
  const int nt = blockIdx.y;
  const unsigned short* Bt = (nt < 8) ? W0 : (nt < 16) ? W1 : W2;
  const int n0 = (nt & 7) * 128;

  fx4 acc[4][4] = {};

  const int srow = w * 8 + (l >> 3);              // row within a 32-row issue block
  const int skb  = ((l & 7) ^ (l >> 3)) * 8;      // pre-swizzled 16B slot (elements)
  const unsigned short* aB = A  + (size_t)(m0 + srow) * 1024 + skb;
  const unsigned short* bB = Bt + (size_t)(n0 + srow) * 1024 + skb;
  unsigned short* aD = &As[w * 512];
  unsigned short* bD = &Bs[w * 512];
  const int rdswz = (l & 7) << 4;

  for (int kt = 0; kt < 1024; kt += 64) {
    __syncthreads();
#pragma unroll
    for (int j = 0; j < 4; ++j) {
      gload_lds16(aB + j * 32768 + kt, aD + j * 2048);
      gload_lds16(bB + j * 32768 + kt, bD + j * 2048);
    }
    __syncthreads();
#pragma unroll
    for (int ks = 0; ks < 2; ++ks) {
      const int kb = (ks * 64 + lg * 16) ^ rdswz;
      s16x8 af[4], bf[4];
#pragma unroll
      for (int mf = 0; mf < 4; ++mf)
        af[mf] = *(const s16x8*)((const char*)As + (wm * 64 + mf * 16 + lr) * 128 + kb);
#pragma unroll
      for (int nf = 0; nf < 4; ++nf)
        bf[nf] = *(const s16x8*)((const char*)Bs + (wn * 64 + nf * 16 + lr) * 128 + kb);
#pragma unroll
      for (int mf = 0; mf < 4; ++mf)
#pragma unroll
        for (int nf = 0; nf < 4; ++nf)
          acc[mf][nf] = __builtin_amdgcn_mfma_f32_16x16x32_bf16(af[mf], bf[nf], acc[mf][nf], 0, 0, 0);
    }
  }

  // C/D layout: row = (l>>4)*4 + reg, col = l&15
  if (MODE == 1) {
    const int gn = nt * 128 + wn * 64;
    const int gm = m0 + wm * 64;
#pragma unroll
    for (int mf = 0; mf < 4; ++mf)
#pragma unroll
      for (int r = 0; r < 4; ++r) {
        int row = gm + mf * 16 + lg * 4 + r;
        float* C = (float*)Cptr + (size_t)row * ldc + gn;
#pragma unroll
        for (int nf = 0; nf < 4; ++nf) C[nf * 16 + lr] = acc[mf][nf][r];
      }
  } else {
    // MODE 2: RMS over the wave's 64-col head block, write to [32][2048][64]
    const int tz = nt >> 3;                       // 0=q 1=k 2=v
    const int h  = ((nt & 7) << 1) | wn;
    const int gm = m0 + wm * 64;
    unsigned short* base = tz == 0 ? qn : tz == 1 ? kn : vb;
    const float cmul = (tz == 0) ? 0.18033688f : 1.0f;   // 0.125 * log2(e)
#pragma unroll
    for (int mf = 0; mf < 4; ++mf)
#pragma unroll
      for (int r = 0; r < 4; ++r) {
        int m = gm + mf * 16 + lg * 4 + r;
        float ss = 0.f;
#pragma unroll
        for (int nf = 0; nf < 4; ++nf) ss += acc[mf][nf][r] * acc[mf][nf][r];
        ss += __shfl_xor(ss, 1);
        ss += __shfl_xor(ss, 2);
        ss += __shfl_xor(ss, 4);
        ss += __shfl_xor(ss, 8);
        float scale = (tz == 2) ? 1.0f : rsqrtf(ss * (1.0f / 64.0f) + 1e-6f) * cmul;
        int b = m >> 11, s = m & 2047;
        unsigned short* dst = base + ((size_t)(((b << 4) + h) * 2048 + s)) * 64;
#pragma unroll
        for (int nf = 0; nf < 4; ++nf)
          dst[nf * 16 + lr] = f2bf(acc[mf][nf][r] * scale);
      }
  }
}

// ---------------- flash attention (causal), split-K, uniform blocks ----------------
// R6-verbatim structure (verified correct twice, 50 us, VGPR 92, 0 conflicts).
// Only change: split-K partials pO stored as bf16 (halves partial traffic;
// accuracy budget: bf16 partial ~0.4% rel, threshold has 5x headroom).
__global__ __launch_bounds__(128, 2)
void k_attn(const unsigned short* __restrict__ Q,   // [32][2048][64], pre-scaled
            const unsigned short* __restrict__ K,
            const unsigned short* __restrict__ V,
            unsigned short* __restrict__ O,         // [2][2048][1024]
            unsigned short* __restrict__ pO,        // [32*16][2][64][64] bf16
            float* __restrict__ pL) {               // [32*16][2][64]
  __shared__ unsigned short Ks[2][64 * 64];     // [kv][dh] swizzled, 8KB each
  __shared__ unsigned short Vt[2][64 * 64];     // [dh][kv'] swizzled, 8KB each
  __shared__ unsigned short Ps[2][32 * 64];     // per-wave P [row][kv'] swizzled, 4KB

  const int id = blockIdx.x;
  const int bh = id >> 5;
  const int c  = id & 31;
  const int p  = c >> 1, half = c & 1;
  const int tid = threadIdx.x;
  const int w = tid >> 6, l = tid & 63;
  const int lr = l & 15, lg = l >> 4;
  const int b = bh >> 4, h = bh & 15;

  const unsigned short* Kb = K + (size_t)bh * 2048 * 64;
  const unsigned short* Vb = V + (size_t)bh * 2048 * 64;
  const unsigned short* Qh = Q + (size_t)bh * 2048 * 64;

  const int ksub = l >> 3;                      // row-within-8 for K staging
  const int kskb = ((l & 7) ^ ksub) * 8;        // pre-swizzled 16B slot (elements)
  const int vc = tid & 31;                      // u32 column (kv' pair index)
  const int vg = tid >> 5;                      // 0..3 dh quarter
  const int kvlo = (vc & 15) + (vc >> 4) * 32;  // kv rows kvlo, kvlo+16
  const int rdswz = (lr & 7) << 4;
  const float FMAX = 11.5415603f;               // 8 * log2(e)

  const int NS = half ? 16 : 17;                // steps for this chunk
  int tile = half ? (31 - p) : p;
  int qw = tile * 64 + w * 32;

  s16x8 aq[2][2];
#pragma unroll
  for (int mf = 0; mf < 2; ++mf)
#pragma unroll
    for (int ks = 0; ks < 2; ++ks)
      aq[mf][ks] = *(const s16x8*)(Qh + (size_t)(qw + mf * 16 + lr) * 64 + ks * 32 + lg * 8);

  fx4 oacc[2][4] = {};
  float lsum[2][4] = {{0.f, 0.f, 0.f, 0.f}, {0.f, 0.f, 0.f, 0.f}};

  int kvt = half ? (16 - p) : 0;                // first KV tile index

  ux4 va0, va1, va2, va3;
  // prologue: stage KV tile kvt into buffer 0
#pragma unroll
  for (int j = 0; j < 4; ++j)
    gload_lds16(Kb + (size_t)(kvt * 64 + j * 16 + w * 8 + ksub) * 64 + kskb,
                &Ks[0][(j * 16 + w * 8) * 64]);
  va0 = *(const ux4*)(Vb + (size_t)(kvt * 64 + kvlo) * 64 + vg * 16);
  va1 = *(const ux4*)(Vb + (size_t)(kvt * 64 + kvlo) * 64 + vg * 16 + 8);
  va2 = *(const ux4*)(Vb + (size_t)(kvt * 64 + kvlo + 16) * 64 + vg * 16);
  va3 = *(const ux4*)(Vb + (size_t)(kvt * 64 + kvlo + 16) * 64 + vg * 16 + 8);
  {
    union { ux4 v; unsigned short u[8]; } a0, a1, a2, a3;
    a0.v = va0; a1.v = va1; a2.v = va2; a3.v = va3;
#pragma unroll
    for (int i = 0; i < 8; ++i) {
      int dh = vg * 16 + i;
      *(unsigned*)((char*)&Vt[0][0] + dh * 128 + ((vc * 4) ^ ((i & 7) << 4))) =
          (unsigned)a0.u[i] | ((unsigned)a2.u[i] << 16);
      *(unsigned*)((char*)&Vt[0][0] + (dh + 8) * 128 + ((vc * 4) ^ ((i & 7) << 4))) =
          (unsigned)a1.u[i] | ((unsigned)a3.u[i] << 16);
    }
  }
  __syncthreads();

#pragma unroll 1
  for (int s = 0; s < NS; ++s) {
    // chunk A: switch from tile p to tile 31-p after tile p's diagonal
    if (!half && s == p + 1) {
      // direct epilogue for tile p (complete causal range covered)
#pragma unroll
      for (int mf = 0; mf < 2; ++mf)
#pragma unroll
        for (int r = 0; r < 4; ++r) {
          float ssum = lsum[mf][r];
          ssum += __shfl_xor(ssum, 1);
          ssum += __shfl_xor(ssum, 2);
          ssum += __shfl_xor(ssum, 4);
          ssum += __shfl_xor(ssum, 8);
          float inv = 1.0f / ssum;
          int gq = qw + mf * 16 + lg * 4 + r;
          unsigned short* orow = O + ((size_t)(b * 2048 + gq)) * 1024 + h * 64;
#pragma unroll
          for (int nf = 0; nf < 4; ++nf)
            orow[nf * 16 + lr] = f2bf(oacc[mf][nf][r] * inv);
        }
      // reset accumulators AFTER all 8 (mf,r) outputs are written (R5 lesson)
#pragma unroll
      for (int mf = 0; mf < 2; ++mf) {
#pragma unroll
        for (int nf = 0; nf < 4; ++nf) oacc[mf][nf] = fx4{0.f, 0.f, 0.f, 0.f};
#pragma unroll
        for (int r = 0; r < 4; ++r) lsum[mf][r] = 0.f;
      }
      tile = 31 - p;
      qw = tile * 64 + w * 32;
#pragma unroll
      for (int mf = 0; mf < 2; ++mf)
#pragma unroll
        for (int ks = 0; ks < 2; ++ks)
          aq[mf][ks] = *(const s16x8*)(Qh + (size_t)(qw + mf * 16 + lr) * 64 + ks * 32 + lg * 8);
    }
    const int cur = s & 1;
    const int kv0 = kvt * 64;
    const bool pre = (s + 1 < NS);
    int nkvt = kvt + 1;
    if (!half && s == p) nkvt = 0;              // jump to tile 31-p's KV start
    if (pre) {
      const int kvn = nkvt * 64;
#pragma unroll
      for (int j = 0; j < 4; ++j)
        gload_lds16(Kb + (size_t)(kvn + j * 16 + w * 8 + ksub) * 64 + kskb,
                    &Ks[cur ^ 1][(j * 16 + w * 8) * 64]);
      va0 = *(const ux4*)(Vb + (size_t)(kvn + kvlo) * 64 + vg * 16);
      va1 = *(const ux4*)(Vb + (size_t)(kvn + kvlo) * 64 + vg * 16 + 8);
      va2 = *(const ux4*)(Vb + (size_t)(kvn + kvlo + 16) * 64 + vg * 16);
      va3 = *(const ux4*)(Vb + (size_t)(kvn + kvlo + 16) * 64 + vg * 16 + 8);
    }
    // QK^T
    fx4 sc[2][4] = {};
    __builtin_amdgcn_s_setprio(1);
#pragma unroll
    for (int ks = 0; ks < 2; ++ks) {
      const int kb = (ks * 64 + lg * 16) ^ rdswz;
#pragma unroll
      for (int nf = 0; nf < 4; ++nf) {
        s16x8 bk = *(const s16x8*)((const char*)&Ks[cur][0] + (nf * 16 + lr) * 128 + kb);
#pragma unroll
        for (int mf = 0; mf < 2; ++mf)
          sc[mf][nf] = __builtin_amdgcn_mfma_f32_16x16x32_bf16(aq[mf][ks], bk, sc[mf][nf], 0, 0, 0);
      }
    }
    __builtin_amdgcn_s_setprio(0);
    const bool diag = half ? (s == 15) : (s == p);
    if (diag) {                                 // diagonal tile: causal mask
#pragma unroll
      for (int mf = 0; mf < 2; ++mf)
#pragma unroll
        for (int nf = 0; nf < 4; ++nf)
#pragma unroll
          for (int r = 0; r < 4; ++r) {
            int gq = qw + mf * 16 + lg * 4 + r;
            int gk = kv0 + nf * 16 + lr;
            if (gk > gq) sc[mf][nf][r] = -3.0e38f;
          }
    }
    // softmax, fixed max; P -> LDS as paired u32 (kv' layout), swizzled
    char* pw = (char*)&Ps[w][0];
#pragma unroll
    for (int mf = 0; mf < 2; ++mf)
#pragma unroll
      for (int r = 0; r < 4; ++r) {
        float p0 = __builtin_amdgcn_exp2f(sc[mf][0][r] - FMAX);
        float p1 = __builtin_amdgcn_exp2f(sc[mf][1][r] - FMAX);
        float p2 = __builtin_amdgcn_exp2f(sc[mf][2][r] - FMAX);
        float p3 = __builtin_amdgcn_exp2f(sc[mf][3][r] - FMAX);
        lsum[mf][r] += (p0 + p1) + (p2 + p3);
        int row = mf * 16 + lg * 4 + r;
        char* pb = pw + row * 128;
        int swz = (row & 7) << 4;
        *(unsigned*)(pb + ((4 * lr) ^ swz))      = (unsigned)f2bf(p0) | ((unsigned)f2bf(p1) << 16);
        *(unsigned*)(pb + ((64 + 4 * lr) ^ swz)) = (unsigned)f2bf(p2) | ((unsigned)f2bf(p3) << 16);
      }
    // PV (A = P rows mf*16+lr over kv', B = Vt rows dh over kv')
    __builtin_amdgcn_s_setprio(1);
#pragma unroll
    for (int ks = 0; ks < 2; ++ks) {
      s16x8 pa[2], bv[4];
#pragma unroll
      for (int mf = 0; mf < 2; ++mf) {
        int row = mf * 16 + lr;
        pa[mf] = *(const s16x8*)(pw + row * 128 + ((ks * 64 + lg * 16) ^ ((row & 7) << 4)));
      }
#pragma unroll
      for (int nf = 0; nf < 4; ++nf) {
        int row = nf * 16 + lr;
        bv[nf] = *(const s16x8*)((const char*)&Vt[cur][0] + row * 128 +
                                 ((ks * 64 + lg * 16) ^ ((row & 7) << 4)));
      }
#pragma unroll
      for (int mf = 0; mf < 2; ++mf)
#pragma unroll
        for (int nf = 0; nf < 4; ++nf)
          oacc[mf][nf] = __builtin_amdgcn_mfma_f32_16x16x32_bf16(pa[mf], bv[nf], oacc[mf][nf], 0, 0, 0);
    }
    __builtin_amdgcn_s_setprio(0);
    if (pre) {                                  // late write of next V tile
      union { ux4 v; unsigned short u[8]; } a0, a1, a2, a3;
      a0.v = va0; a1.v = va1; a2.v = va2; a3.v = va3;
#pragma unroll
      for (int i = 0; i < 8; ++i) {
        int dh = vg * 16 + i;
        *(unsigned*)((char*)&Vt[cur ^ 1][0] + dh * 128 + ((vc * 4) ^ ((i & 7) << 4))) =
            (unsigned)a0.u[i] | ((unsigned)a2.u[i] << 16);
        *(unsigned*)((char*)&Vt[cur ^ 1][0] + (dh + 8) * 128 + ((vc * 4) ^ ((i & 7) << 4))) =
            (unsigned)a1.u[i] | ((unsigned)a3.u[i] << 16);
      }
    }
    kvt = nkvt;
    __syncthreads();
  }

  // final epilogue: write bf16 partials for tile 31-p
  const int slot = ((bh * 16 + p) * 2 + half);
#pragma unroll
  for (int mf = 0; mf < 2; ++mf)
#pragma unroll
    for (int r = 0; r < 4; ++r) {
      float ssum = lsum[mf][r];
      ssum += __shfl_xor(ssum, 1);
      ssum += __shfl_xor(ssum, 2);
      ssum += __shfl_xor(ssum, 4);
      ssum += __shfl_xor(ssum, 8);
      int row = w * 32 + mf * 16 + lg * 4 + r;  // 0..63 within tile
      unsigned short* po = pO + ((size_t)slot * 64 + row) * 64;
#pragma unroll
      for (int nf = 0; nf < 4; ++nf) po[nf * 16 + lr] = f2bf(oacc[mf][nf][r]);
      if (lr == 0) pL[slot * 64 + row] = ssum;
    }
}

// ---------------- merge split-K partials for tiles 16..31 (bf16 partials) ----------
__global__ __launch_bounds__(256)
void k_merge(const unsigned short* __restrict__ pO, const float* __restrict__ pL,
             unsigned short* __restrict__ O) {
  int gid = blockIdx.x * 256 + threadIdx.x;     // 524288 = 32768 rows x 16 quads
  int row = gid >> 4;                           // (bh*16 + p)*64 + r
  int quad = gid & 15;
  int slot = row >> 6;                          // bh*16 + p
  int r = row & 63;
  int bh = slot >> 4, p = slot & 15;
  const unsigned short* pa = pO + ((size_t)(slot * 2) * 64 + r) * 64 + quad * 4;
  const unsigned short* pb = pO + ((size_t)(slot * 2 + 1) * 64 + r) * 64 + quad * 4;
  ux2 ua = *(const ux2*)pa;
  ux2 ub = *(const ux2*)pb;
  float inv = 1.0f / (pL[(slot * 2) * 64 + r] + pL[(slot * 2 + 1) * 64 + r]);
  int tile = 31 - p;
  int b = bh >> 4, h = bh & 15;
  int s = tile * 64 + r;
  unsigned short* o = O + ((size_t)(b * 2048 + s)) * 1024 + h * 64 + quad * 4;
  float v0 = (bf2f((unsigned short)(ua[0] & 0xffff)) + bf2f((unsigned short)(ub[0] & 0xffff))) * inv;
  float v1 = (bf2f((unsigned short)(ua[0] >> 16))   + bf2f((unsigned short)(ub[0] >> 16)))   * inv;
  float v2 = (bf2f((unsigned short)(ua[1] & 0xffff)) + bf2f((unsigned short)(ub[1] & 0xffff))) * inv;
  float v3 = (bf2f((unsigned short)(ua[1] >> 16))   + bf2f((unsigned short)(ub[1] >> 16)))   * inv;
  ux2 out;
  out[0] = (unsigned)f2bf(v0) | ((unsigned)f2bf(v1) << 16);
  out[1] = (unsigned)f2bf(v2) | ((unsigned)f2bf(v3) << 16);
  *(ux2*)o = out;
}

// ---------------- launch ----------------
extern "C" void kernel_launch(void* const* d_in, const int* in_sizes, int n_in,
                              void* d_out, int out_size, void* d_ws, size_t ws_size,
                              hipStream_t stream) {
  const float* x  = (const float*)d_in[0];
  const float* Wq = (const float*)d_in[1];
  const float* Wk = (const float*)d_in[2];
  const float* Wv = (const float*)d_in[3];
  const float* Wo = (const float*)d_in[4];
  // d_in[5] = causal mask (tril) — implemented analytically.

  char* ws = (char*)d_ws;                                  // ~57 MB
  unsigned short* xb   = (unsigned short*)(ws);            // 8 MB  [4096][1024]
  unsigned short* WqT  = (unsigned short*)(ws + (8ll  << 20));
  unsigned short* WkT  = (unsigned short*)(ws + (10ll << 20));
  unsigned short* WvT  = (unsigned short*)(ws + (12ll << 20));
  unsigned short* WoT  = (unsigned short*)(ws + (14ll << 20));
  unsigned short* qn   = (unsigned short*)(ws + (16ll << 20)); // 8 MB [32][2048][64]
  unsigned short* kn   = (unsigned short*)(ws + (24ll << 20));
  unsigned short* vb   = (unsigned short*)(ws + (32ll << 20));
  unsigned short* attn = (unsigned short*)(ws + (40ll << 20)); // 8 MB [4096][1024]
  unsigned short* pO   = (unsigned short*)(ws + (48ll << 20)); // 8 MB bf16 partials
  float* pL            = (float*)(ws + (56ll << 20));          // 256 KB

  k_conv_bf16<<<1024, 256, 0, stream>>>(x, xb, 4096 * 1024 / 4);
  k_transpose_w<<<dim3(32, 32, 4), dim3(32, 8), 0, stream>>>(Wq, Wk, Wv, Wo, WqT, WkT, WvT, WoT);
  k_gemm_bt<2><<<dim3(32, 24), 256, 0, stream>>>(xb, WqT, WkT, WvT, nullptr, 0, qn, kn, vb);
  k_attn<<<1024, 128, 0, stream>>>(qn, kn, vb, attn, pO, pL);
  k_merge<<<2048, 256, 0, stream>>>(pO, pL, attn);
  k_gemm_bt<1><<<dim3(32, 8), 256, 0, stream>>>(attn, WoT, WoT, WoT, d_out, 1024, nullptr, nullptr, nullptr);
}

// Round 12
// 107.804 us; speedup vs baseline: 1.2833x; 1.0248x over previous
//
#include <hip/hip_runtime.h>
#include <stdint.h>

// Problem constants: B=2, S=2048, D=1024, H=16, DH=64; M = B*S = 4096.

typedef __attribute__((ext_vector_type(8))) short s16x8;   // 8 bf16 (MFMA A/B frag)
typedef __attribute__((ext_vector_type(4))) float fx4;     // MFMA C/D frag
typedef __attribute__((ext_vector_type(4))) unsigned int ux4;
typedef __attribute__((ext_vector_type(2))) unsigned int ux2;

__device__ __forceinline__ unsigned short f2bf(float x) {
  unsigned u = __builtin_bit_cast(unsigned, x);
  u += 0x7fffu + ((u >> 16) & 1u);          // RNE
  return (unsigned short)(u >> 16);
}
__device__ __forceinline__ float bf2f(unsigned short h) {
  return __builtin_bit_cast(float, (unsigned)h << 16);
}

// async global->LDS, 16B per lane; LDS dest = wave-uniform base + lane*16
__device__ __forceinline__ void gload_lds16(const void* g, void* l) {
  __builtin_amdgcn_global_load_lds(
      (const __attribute__((address_space(1))) unsigned int*)g,
      (__attribute__((address_space(3))) unsigned int*)l, 16, 0, 0);
}

// ---------------- fused prep: x f32->bf16 + 4x weight transpose ----------------
// blocks 0..4095: conv, one fx4/thread -> 4096*256 = 1,048,576 quads = ALL of x.
// blocks 4096..8191: 32x32 transpose tiles for the 4 weights.
__global__ void k_prep(const float* __restrict__ X, unsigned short* __restrict__ Y,
                       const float* __restrict__ W0, const float* __restrict__ W1,
                       const float* __restrict__ W2, const float* __restrict__ W3,
                       unsigned short* __restrict__ T0, unsigned short* __restrict__ T1,
                       unsigned short* __restrict__ T2, unsigned short* __restrict__ T3) {
  __shared__ float t[32][33];
  int bid = blockIdx.x;
  int tid = threadIdx.x;
  if (bid < 4096) {
    int i = bid * 256 + tid;                    // exact cover of 1,048,576 quads
    fx4 v = *(const fx4*)(X + (size_t)i * 4);
    ux2 o;
    o[0] = (unsigned)f2bf(v[0]) | ((unsigned)f2bf(v[1]) << 16);
    o[1] = (unsigned)f2bf(v[2]) | ((unsigned)f2bf(v[3]) << 16);
    *(ux2*)(Y + (size_t)i * 4) = o;
    return;
  }
  int r = bid - 4096;
  int z = r >> 10;
  int rem = r & 1023;
  const float* W = z == 0 ? W0 : z == 1 ? W1 : z == 2 ? W2 : W3;
  unsigned short* T = z == 0 ? T0 : z == 1 ? T1 : z == 2 ? T2 : T3;
  int bx = (rem & 31) * 32, by = (rem >> 5) * 32;
  int tx = tid & 31, ty = tid >> 5;             // (32,8)
#pragma unroll
  for (int i = 0; i < 32; i += 8)
    t[ty + i][tx] = W[(size_t)(by + ty + i) * 1024 + bx + tx];
  __syncthreads();
#pragma unroll
  for (int i = 0; i < 32; i += 8)
    T[(size_t)(bx + ty + i) * 1024 + by + tx] = f2bf(t[tx][ty + i]);
}

// ---------------- GEMM: C[M x Ntot] = A[M x 1024] * Wt ----
// tile 128x128, BK=64, 256 thr (4 waves 2x2 of 64x64), mfma 16x16x32 bf16.
// launch_bounds(256,3): cap VGPR ~170 so 3 blocks/CU co-reside.
// MODE 1: f32 C store. MODE 2: fused RMSNorm-over-64 + split to qn/kn/vb.
template <int MODE>
__global__ __launch_bounds__(256, 3)
void k_gemm_bt(const unsigned short* __restrict__ A,
               const unsigned short* __restrict__ W0,
               const unsigned short* __restrict__ W1,
               const unsigned short* __restrict__ W2,
               void* __restrict__ Cptr, int ldc,
               unsigned short* __restrict__ qn, unsigned short* __restrict__ kn,
               unsigned short* __restrict__ vb) {
  __shared__ unsigned short As[128 * 64];
  __shared__ unsigned short Bs[128 * 64];
  const int tid = threadIdx.x;
  const int w = tid >> 6, l = tid & 63;
  const int lr = l & 15, lg = l >> 4;
  const int wm = w >> 1, wn = w & 1;
  const int m0 = blockIdx.x * 128;
  const int nt = blockIdx.y;
  const unsigned short* Bt = (nt < 8) ? W0 : (nt < 16) ? W1 : W2;
  const int n0 = (nt & 7) * 128;

  fx4 acc[4][4] = {};

  const int srow = w * 8 + (l >> 3);              // row within a 32-row issue block
  const int skb  = ((l & 7) ^ (l >> 3)) * 8;      // pre-swizzled 16B slot (elements)
  const unsigned short* aB = A  + (size_t)(m0 + srow) * 1024 + skb;
  const unsigned short* bB = Bt + (size_t)(n0 + srow) * 1024 + skb;
  unsigned short* aD = &As[w * 512];
  unsigned short* bD = &Bs[w * 512];
  const int rdswz = (l & 7) << 4;

  for (int kt = 0; kt < 1024; kt += 64) {
    __syncthreads();
#pragma unroll
    for (int j = 0; j < 4; ++j) {
      gload_lds16(aB + j * 32768 + kt, aD + j * 2048);
      gload_lds16(bB + j * 32768 + kt, bD + j * 2048);
    }
    __syncthreads();
#pragma unroll
    for (int ks = 0; ks < 2; ++ks) {
      const int kb = (ks * 64 + lg * 16) ^ rdswz;
      s16x8 af[4], bf[4];
#pragma unroll
      for (int mf = 0; mf < 4; ++mf)
        af[mf] = *(const s16x8*)((const char*)As + (wm * 64 + mf * 16 + lr) * 128 + kb);
#pragma unroll
      for (int nf = 0; nf < 4; ++nf)
        bf[nf] = *(const s16x8*)((const char*)Bs + (wn * 64 + nf * 16 + lr) * 128 + kb);
#pragma unroll
      for (int mf = 0; mf < 4; ++mf)
#pragma unroll
        for (int nf = 0; nf < 4; ++nf)
          acc[mf][nf] = __builtin_amdgcn_mfma_f32_16x16x32_bf16(af[mf], bf[nf], acc[mf][nf], 0, 0, 0);
    }
  }

  // C/D layout: row = (l>>4)*4 + reg, col = l&15
  if (MODE == 1) {
    const int gn = nt * 128 + wn * 64;
    const int gm = m0 + wm * 64;
#pragma unroll
    for (int mf = 0; mf < 4; ++mf)
#pragma unroll
      for (int r = 0; r < 4; ++r) {
        int row = gm + mf * 16 + lg * 4 + r;
        float* C = (float*)Cptr + (size_t)row * ldc + gn;
#pragma unroll
        for (int nf = 0; nf < 4; ++nf) C[nf * 16 + lr] = acc[mf][nf][r];
      }
  } else {
    // MODE 2: RMS over the wave's 64-col head block, write to [32][2048][64]
    const int tz = nt >> 3;                       // 0=q 1=k 2=v
    const int h  = ((nt & 7) << 1) | wn;
    const int gm = m0 + wm * 64;
    unsigned short* base = tz == 0 ? qn : tz == 1 ? kn : vb;
    const float cmul = (tz == 0) ? 0.18033688f : 1.0f;   // 0.125 * log2(e)
#pragma unroll
    for (int mf = 0; mf < 4; ++mf)
#pragma unroll
      for (int r = 0; r < 4; ++r) {
        int m = gm + mf * 16 + lg * 4 + r;
        float ss = 0.f;
#pragma unroll
        for (int nf = 0; nf < 4; ++nf) ss += acc[mf][nf][r] * acc[mf][nf][r];
        ss += __shfl_xor(ss, 1);
        ss += __shfl_xor(ss, 2);
        ss += __shfl_xor(ss, 4);
        ss += __shfl_xor(ss, 8);
        float scale = (tz == 2) ? 1.0f : rsqrtf(ss * (1.0f / 64.0f) + 1e-6f) * cmul;
        int b = m >> 11, s = m & 2047;
        unsigned short* dst = base + ((size_t)(((b << 4) + h) * 2048 + s)) * 64;
#pragma unroll
        for (int nf = 0; nf < 4; ++nf)
          dst[nf * 16 + lr] = f2bf(acc[mf][nf][r] * scale);
      }
  }
}

// ---------------- flash attention (causal), split-K, uniform blocks ----------------
// R9-exact kernel (replay-validated at 110.5 us total): R6 structure, bf16 partials.
__global__ __launch_bounds__(128, 2)
void k_attn(const unsigned short* __restrict__ Q,   // [32][2048][64], pre-scaled
            const unsigned short* __restrict__ K,
            const unsigned short* __restrict__ V,
            unsigned short* __restrict__ O,         // [2][2048][1024]
            unsigned short* __restrict__ pO,        // [32*16][2][64][64] bf16
            float* __restrict__ pL) {               // [32*16][2][64]
  __shared__ unsigned short Ks[2][64 * 64];     // [kv][dh] swizzled, 8KB each
  __shared__ unsigned short Vt[2][64 * 64];     // [dh][kv'] swizzled, 8KB each
  __shared__ unsigned short Ps[2][32 * 64];     // per-wave P [row][kv'] swizzled, 4KB

  const int id = blockIdx.x;
  const int bh = id >> 5;
  const int c  = id & 31;
  const int p  = c >> 1, half = c & 1;
  const int tid = threadIdx.x;
  const int w = tid >> 6, l = tid & 63;
  const int lr = l & 15, lg = l >> 4;
  const int b = bh >> 4, h = bh & 15;

  const unsigned short* Kb = K + (size_t)bh * 2048 * 64;
  const unsigned short* Vb = V + (size_t)bh * 2048 * 64;
  const unsigned short* Qh = Q + (size_t)bh * 2048 * 64;

  const int ksub = l >> 3;                      // row-within-8 for K staging
  const int kskb = ((l & 7) ^ ksub) * 8;        // pre-swizzled 16B slot (elements)
  const int vc = tid & 31;                      // u32 column (kv' pair index)
  const int vg = tid >> 5;                      // 0..3 dh quarter
  const int kvlo = (vc & 15) + (vc >> 4) * 32;  // kv rows kvlo, kvlo+16
  const int rdswz = (lr & 7) << 4;
  const float FMAX = 11.5415603f;               // 8 * log2(e)

  const int NS = half ? 16 : 17;                // steps for this chunk
  int tile = half ? (31 - p) : p;
  int qw = tile * 64 + w * 32;

  s16x8 aq[2][2];
#pragma unroll
  for (int mf = 0; mf < 2; ++mf)
#pragma unroll
    for (int ks = 0; ks < 2; ++ks)
      aq[mf][ks] = *(const s16x8*)(Qh + (size_t)(qw + mf * 16 + lr) * 64 + ks * 32 + lg * 8);

  fx4 oacc[2][4] = {};
  float lsum[2][4] = {{0.f, 0.f, 0.f, 0.f}, {0.f, 0.f, 0.f, 0.f}};

  int kvt = half ? (16 - p) : 0;                // first KV tile index

  ux4 va0, va1, va2, va3;
  // prologue: stage KV tile kvt into buffer 0
#pragma unroll
  for (int j = 0; j < 4; ++j)
    gload_lds16(Kb + (size_t)(kvt * 64 + j * 16 + w * 8 + ksub) * 64 + kskb,
                &Ks[0][(j * 16 + w * 8) * 64]);
  va0 = *(const ux4*)(Vb + (size_t)(kvt * 64 + kvlo) * 64 + vg * 16);
  va1 = *(const ux4*)(Vb + (size_t)(kvt * 64 + kvlo) * 64 + vg * 16 + 8);
  va2 = *(const ux4*)(Vb + (size_t)(kvt * 64 + kvlo + 16) * 64 + vg * 16);
  va3 = *(const ux4*)(Vb + (size_t)(kvt * 64 + kvlo + 16) * 64 + vg * 16 + 8);
  {
    union { ux4 v; unsigned short u[8]; } a0, a1, a2, a3;
    a0.v = va0; a1.v = va1; a2.v = va2; a3.v = va3;
#pragma unroll
    for (int i = 0; i < 8; ++i) {
      int dh = vg * 16 + i;
      *(unsigned*)((char*)&Vt[0][0] + dh * 128 + ((vc * 4) ^ ((i & 7) << 4))) =
          (unsigned)a0.u[i] | ((unsigned)a2.u[i] << 16);
      *(unsigned*)((char*)&Vt[0][0] + (dh + 8) * 128 + ((vc * 4) ^ ((i & 7) << 4))) =
          (unsigned)a1.u[i] | ((unsigned)a3.u[i] << 16);
    }
  }
  __syncthreads();

#pragma unroll 1
  for (int s = 0; s < NS; ++s) {
    // chunk A: switch from tile p to tile 31-p after tile p's diagonal
    if (!half && s == p + 1) {
      // direct epilogue for tile p (complete causal range covered)
#pragma unroll
      for (int mf = 0; mf < 2; ++mf)
#pragma unroll
        for (int r = 0; r < 4; ++r) {
          float ssum = lsum[mf][r];
          ssum += __shfl_xor(ssum, 1);
          ssum += __shfl_xor(ssum, 2);
          ssum += __shfl_xor(ssum, 4);
          ssum += __shfl_xor(ssum, 8);
          float inv = 1.0f / ssum;
          int gq = qw + mf * 16 + lg * 4 + r;
          unsigned short* orow = O + ((size_t)(b * 2048 + gq)) * 1024 + h * 64;
#pragma unroll
          for (int nf = 0; nf < 4; ++nf)
            orow[nf * 16 + lr] = f2bf(oacc[mf][nf][r] * inv);
        }
      // reset accumulators AFTER all 8 (mf,r) outputs are written (R5 lesson)
#pragma unroll
      for (int mf = 0; mf < 2; ++mf) {
#pragma unroll
        for (int nf = 0; nf < 4; ++nf) oacc[mf][nf] = fx4{0.f, 0.f, 0.f, 0.f};
#pragma unroll
        for (int r = 0; r < 4; ++r) lsum[mf][r] = 0.f;
      }
      tile = 31 - p;
      qw = tile * 64 + w * 32;
#pragma unroll
      for (int mf = 0; mf < 2; ++mf)
#pragma unroll
        for (int ks = 0; ks < 2; ++ks)
          aq[mf][ks] = *(const s16x8*)(Qh + (size_t)(qw + mf * 16 + lr) * 64 + ks * 32 + lg * 8);
    }
    const int cur = s & 1;
    const int kv0 = kvt * 64;
    const bool pre = (s + 1 < NS);
    int nkvt = kvt + 1;
    if (!half && s == p) nkvt = 0;              // jump to tile 31-p's KV start
    if (pre) {
      const int kvn = nkvt * 64;
#pragma unroll
      for (int j = 0; j < 4; ++j)
        gload_lds16(Kb + (size_t)(kvn + j * 16 + w * 8 + ksub) * 64 + kskb,
                    &Ks[cur ^ 1][(j * 16 + w * 8) * 64]);
      va0 = *(const ux4*)(Vb + (size_t)(kvn + kvlo) * 64 + vg * 16);
      va1 = *(const ux4*)(Vb + (size_t)(kvn + kvlo) * 64 + vg * 16 + 8);
      va2 = *(const ux4*)(Vb + (size_t)(kvn + kvlo + 16) * 64 + vg * 16);
      va3 = *(const ux4*)(Vb + (size_t)(kvn + kvlo + 16) * 64 + vg * 16 + 8);
    }
    // QK^T
    fx4 sc[2][4] = {};
    __builtin_amdgcn_s_setprio(1);
#pragma unroll
    for (int ks = 0; ks < 2; ++ks) {
      const int kb = (ks * 64 + lg * 16) ^ rdswz;
#pragma unroll
      for (int nf = 0; nf < 4; ++nf) {
        s16x8 bk = *(const s16x8*)((const char*)&Ks[cur][0] + (nf * 16 + lr) * 128 + kb);
#pragma unroll
        for (int mf = 0; mf < 2; ++mf)
          sc[mf][nf] = __builtin_amdgcn_mfma_f32_16x16x32_bf16(aq[mf][ks], bk, sc[mf][nf], 0, 0, 0);
      }
    }
    __builtin_amdgcn_s_setprio(0);
    const bool diag = half ? (s == 15) : (s == p);
    if (diag) {                                 // diagonal tile: causal mask
#pragma unroll
      for (int mf = 0; mf < 2; ++mf)
#pragma unroll
        for (int nf = 0; nf < 4; ++nf)
#pragma unroll
          for (int r = 0; r < 4; ++r) {
            int gq = qw + mf * 16 + lg * 4 + r;
            int gk = kv0 + nf * 16 + lr;
            if (gk > gq) sc[mf][nf][r] = -3.0e38f;
          }
    }
    // softmax, fixed max; P -> LDS as paired u32 (kv' layout), swizzled
    char* pw = (char*)&Ps[w][0];
#pragma unroll
    for (int mf = 0; mf < 2; ++mf)
#pragma unroll
      for (int r = 0; r < 4; ++r) {
        float p0 = __builtin_amdgcn_exp2f(sc[mf][0][r] - FMAX);
        float p1 = __builtin_amdgcn_exp2f(sc[mf][1][r] - FMAX);
        float p2 = __builtin_amdgcn_exp2f(sc[mf][2][r] - FMAX);
        float p3 = __builtin_amdgcn_exp2f(sc[mf][3][r] - FMAX);
        lsum[mf][r] += (p0 + p1) + (p2 + p3);
        int row = mf * 16 + lg * 4 + r;
        char* pb = pw + row * 128;
        int swz = (row & 7) << 4;
        *(unsigned*)(pb + ((4 * lr) ^ swz))      = (unsigned)f2bf(p0) | ((unsigned)f2bf(p1) << 16);
        *(unsigned*)(pb + ((64 + 4 * lr) ^ swz)) = (unsigned)f2bf(p2) | ((unsigned)f2bf(p3) << 16);
      }
    // PV (A = P rows mf*16+lr over kv', B = Vt rows dh over kv')
    __builtin_amdgcn_s_setprio(1);
#pragma unroll
    for (int ks = 0; ks < 2; ++ks) {
      s16x8 pa[2], bv[4];
#pragma unroll
      for (int mf = 0; mf < 2; ++mf) {
        int row = mf * 16 + lr;
        pa[mf] = *(const s16x8*)(pw + row * 128 + ((ks * 64 + lg * 16) ^ ((row & 7) << 4)));
      }
#pragma unroll
      for (int nf = 0; nf < 4; ++nf) {
        int row = nf * 16 + lr;
        bv[nf] = *(const s16x8*)((const char*)&Vt[cur][0] + row * 128 +
                                 ((ks * 64 + lg * 16) ^ ((row & 7) << 4)));
      }
#pragma unroll
      for (int mf = 0; mf < 2; ++mf)
#pragma unroll
        for (int nf = 0; nf < 4; ++nf)
          oacc[mf][nf] = __builtin_amdgcn_mfma_f32_16x16x32_bf16(pa[mf], bv[nf], oacc[mf][nf], 0, 0, 0);
    }
    __builtin_amdgcn_s_setprio(0);
    if (pre) {                                  // late write of next V tile
      union { ux4 v; unsigned short u[8]; } a0, a1, a2, a3;
      a0.v = va0; a1.v = va1; a2.v = va2; a3.v = va3;
#pragma unroll
      for (int i = 0; i < 8; ++i) {
        int dh = vg * 16 + i;
        *(unsigned*)((char*)&Vt[cur ^ 1][0] + dh * 128 + ((vc * 4) ^ ((i & 7) << 4))) =
            (unsigned)a0.u[i] | ((unsigned)a2.u[i] << 16);
        *(unsigned*)((char*)&Vt[cur ^ 1][0] + (dh + 8) * 128 + ((vc * 4) ^ ((i & 7) << 4))) =
            (unsigned)a1.u[i] | ((unsigned)a3.u[i] << 16);
      }
    }
    kvt = nkvt;
    __syncthreads();
  }

  // final epilogue: write bf16 partials for tile 31-p
  const int slot = ((bh * 16 + p) * 2 + half);
#pragma unroll
  for (int mf = 0; mf < 2; ++mf)
#pragma unroll
    for (int r = 0; r < 4; ++r) {
      float ssum = lsum[mf][r];
      ssum += __shfl_xor(ssum, 1);
      ssum += __shfl_xor(ssum, 2);
      ssum += __shfl_xor(ssum, 4);
      ssum += __shfl_xor(ssum, 8);
      int row = w * 32 + mf * 16 + lg * 4 + r;  // 0..63 within tile
      unsigned short* po = pO + ((size_t)slot * 64 + row) * 64;
#pragma unroll
      for (int nf = 0; nf < 4; ++nf) po[nf * 16 + lr] = f2bf(oacc[mf][nf][r]);
      if (lr == 0) pL[slot * 64 + row] = ssum;
    }
}

// ---------------- merge split-K partials for tiles 16..31 (bf16 partials) ----------
__global__ __launch_bounds__(256)
void k_merge(const unsigned short* __restrict__ pO, const float* __restrict__ pL,
             unsigned short* __restrict__ O) {
  int gid = blockIdx.x * 256 + threadIdx.x;     // 524288 = 32768 rows x 16 quads
  int row = gid >> 4;                           // (bh*16 + p)*64 + r
  int quad = gid & 15;
  int slot = row >> 6;                          // bh*16 + p
  int r = row & 63;
  int bh = slot >> 4, p = slot & 15;
  const unsigned short* pa = pO + ((size_t)(slot * 2) * 64 + r) * 64 + quad * 4;
  const unsigned short* pb = pO + ((size_t)(slot * 2 + 1) * 64 + r) * 64 + quad * 4;
  ux2 ua = *(const ux2*)pa;
  ux2 ub = *(const ux2*)pb;
  float inv = 1.0f / (pL[(slot * 2) * 64 + r] + pL[(slot * 2 + 1) * 64 + r]);
  int tile = 31 - p;
  int b = bh >> 4, h = bh & 15;
  int s = tile * 64 + r;
  unsigned short* o = O + ((size_t)(b * 2048 + s)) * 1024 + h * 64 + quad * 4;
  float v0 = (bf2f((unsigned short)(ua[0] & 0xffff)) + bf2f((unsigned short)(ub[0] & 0xffff))) * inv;
  float v1 = (bf2f((unsigned short)(ua[0] >> 16))   + bf2f((unsigned short)(ub[0] >> 16)))   * inv;
  float v2 = (bf2f((unsigned short)(ua[1] & 0xffff)) + bf2f((unsigned short)(ub[1] & 0xffff))) * inv;
  float v3 = (bf2f((unsigned short)(ua[1] >> 16))   + bf2f((unsigned short)(ub[1] >> 16)))   * inv;
  ux2 out;
  out[0] = (unsigned)f2bf(v0) | ((unsigned)f2bf(v1) << 16);
  out[1] = (unsigned)f2bf(v2) | ((unsigned)f2bf(v3) << 16);
  *(ux2*)o = out;
}

// ---------------- launch ----------------
extern "C" void kernel_launch(void* const* d_in, const int* in_sizes, int n_in,
                              void* d_out, int out_size, void* d_ws, size_t ws_size,
                              hipStream_t stream) {
  const float* x  = (const float*)d_in[0];
  const float* Wq = (const float*)d_in[1];
  const float* Wk = (const float*)d_in[2];
  const float* Wv = (const float*)d_in[3];
  const float* Wo = (const float*)d_in[4];
  // d_in[5] = causal mask (tril) — implemented analytically.

  char* ws = (char*)d_ws;                                  // ~57 MB
  unsigned short* xb   = (unsigned short*)(ws);            // 8 MB  [4096][1024]
  unsigned short* WqT  = (unsigned short*)(ws + (8ll  << 20));
  unsigned short* WkT  = (unsigned short*)(ws + (10ll << 20));
  unsigned short* WvT  = (unsigned short*)(ws + (12ll << 20));
  unsigned short* WoT  = (unsigned short*)(ws + (14ll << 20));
  unsigned short* qn   = (unsigned short*)(ws + (16ll << 20)); // 8 MB [32][2048][64]
  unsigned short* kn   = (unsigned short*)(ws + (24ll << 20));
  unsigned short* vb   = (unsigned short*)(ws + (32ll << 20));
  unsigned short* attn = (unsigned short*)(ws + (40ll << 20)); // 8 MB [4096][1024]
  unsigned short* pO   = (unsigned short*)(ws + (48ll << 20)); // 8 MB bf16 partials
  float* pL            = (float*)(ws + (56ll << 20));          // 256 KB

  k_prep<<<8192, 256, 0, stream>>>(x, xb, Wq, Wk, Wv, Wo, WqT, WkT, WvT, WoT);
  k_gemm_bt<2><<<dim3(32, 24), 256, 0, stream>>>(xb, WqT, WkT, WvT, nullptr, 0, qn, kn, vb);
  k_attn<<<1024, 128, 0, stream>>>(qn, kn, vb, attn, pO, pL);
  k_merge<<<2048, 256, 0, stream>>>(pO, pL, attn);
  k_gemm_bt<1><<<dim3(32, 8), 256, 0, stream>>>(attn, WoT, WoT, WoT, d_out, 1024, nullptr, nullptr, nullptr);
}

// Round 14
// 103.989 us; speedup vs baseline: 1.3304x; 1.0367x over previous
//
#include <hip/hip_runtime.h>
#include <stdint.h>

// Problem constants: B=2, S=2048, D=1024, H=16, DH=64; M = B*S = 4096.

typedef __attribute__((ext_vector_type(8))) short s16x8;   // 8 bf16 (MFMA A/B frag)
typedef __attribute__((ext_vector_type(4))) float fx4;     // MFMA C/D frag
typedef __attribute__((ext_vector_type(4))) unsigned int ux4;
typedef __attribute__((ext_vector_type(2))) unsigned int ux2;

__device__ __forceinline__ unsigned short f2bf(float x) {
  unsigned u = __builtin_bit_cast(unsigned, x);
  u += 0x7fffu + ((u >> 16) & 1u);          // RNE
  return (unsigned short)(u >> 16);
}
__device__ __forceinline__ float bf2f(unsigned short h) {
  return __builtin_bit_cast(float, (unsigned)h << 16);
}

// async global->LDS, 16B per lane; LDS dest = wave-uniform base + lane*16
__device__ __forceinline__ void gload_lds16(const void* g, void* l) {
  __builtin_amdgcn_global_load_lds(
      (const __attribute__((address_space(1))) unsigned int*)g,
      (__attribute__((address_space(3))) unsigned int*)l, 16, 0, 0);
}

// ---------------- fused prep: x f32->bf16 + 4x weight transpose ----------------
// blocks 0..4095: conv, one fx4/thread -> 4096*256 = 1,048,576 quads = ALL of x.
// blocks 4096..8191: 32x32 transpose tiles for the 4 weights.
__global__ void k_prep(const float* __restrict__ X, unsigned short* __restrict__ Y,
                       const float* __restrict__ W0, const float* __restrict__ W1,
                       const float* __restrict__ W2, const float* __restrict__ W3,
                       unsigned short* __restrict__ T0, unsigned short* __restrict__ T1,
                       unsigned short* __restrict__ T2, unsigned short* __restrict__ T3) {
  __shared__ float t[32][33];
  int bid = blockIdx.x;
  int tid = threadIdx.x;
  if (bid < 4096) {
    int i = bid * 256 + tid;                    // exact cover of 1,048,576 quads
    fx4 v = *(const fx4*)(X + (size_t)i * 4);
    ux2 o;
    o[0] = (unsigned)f2bf(v[0]) | ((unsigned)f2bf(v[1]) << 16);
    o[1] = (unsigned)f2bf(v[2]) | ((unsigned)f2bf(v[3]) << 16);
    *(ux2*)(Y + (size_t)i * 4) = o;
    return;
  }
  int r = bid - 4096;
  int z = r >> 10;
  int rem = r & 1023;
  const float* W = z == 0 ? W0 : z == 1 ? W1 : z == 2 ? W2 : W3;
  unsigned short* T = z == 0 ? T0 : z == 1 ? T1 : z == 2 ? T2 : T3;
  int bx = (rem & 31) * 32, by = (rem >> 5) * 32;
  int tx = tid & 31, ty = tid >> 5;             // (32,8)
#pragma unroll
  for (int i = 0; i < 32; i += 8)
    t[ty + i][tx] = W[(size_t)(by + ty + i) * 1024 + bx + tx];
  __syncthreads();
#pragma unroll
  for (int i = 0; i < 32; i += 8)
    T[(size_t)(bx + ty + i) * 1024 + by + tx] = f2bf(t[tx][ty + i]);
}

// ---------------- GEMM: C[M x Ntot] = A[M x 1024] * Wt ----
// tile 128x128, BK=64, 256 thr (4 waves 2x2 of 64x64), mfma 16x16x32 bf16.
// launch_bounds(256,3): cap VGPR ~170 so 3 blocks/CU co-reside.
// MODE 1: f32 C store. MODE 2: fused RMSNorm-over-64 + split to qn/kn/vb.
template <int MODE>
__global__ __launch_bounds__(256, 3)
void k_gemm_bt(const unsigned short* __restrict__ A,
               const unsigned short* __restrict__ W0,
               const unsigned short* __restrict__ W1,
               const unsigned short* __restrict__ W2,
               void* __restrict__ Cptr, int ldc,
               unsigned short* __restrict__ qn, unsigned short* __restrict__ kn,
               unsigned short* __restrict__ vb) {
  __shared__ unsigned short As[128 * 64];
  __shared__ unsigned short Bs[128 * 64];
  const int tid = threadIdx.x;
  const int w = tid >> 6, l = tid & 63;
  const int lr = l & 15, lg = l >> 4;
  const int wm = w >> 1, wn = w & 1;
  const int m0 = blockIdx.x * 128;
  const int nt = blockIdx.y;
  const unsigned short* Bt = (nt < 8) ? W0 : (nt < 16) ? W1 : W2;
  const int n0 = (nt & 7) * 128;

  fx4 acc[4][4] = {};

  const int srow = w * 8 + (l >> 3);              // row within a 32-row issue block
  const int skb  = ((l & 7) ^ (l >> 3)) * 8;      // pre-swizzled 16B slot (elements)
  const unsigned short* aB = A  + (size_t)(m0 + srow) * 1024 + skb;
  const unsigned short* bB = Bt + (size_t)(n0 + srow) * 1024 + skb;
  unsigned short* aD = &As[w * 512];
  unsigned short* bD = &Bs[w * 512];
  const int rdswz = (l & 7) << 4;

  for (int kt = 0; kt < 1024; kt += 64) {
    __syncthreads();
#pragma unroll
    for (int j = 0; j < 4; ++j) {
      gload_lds16(aB + j * 32768 + kt, aD + j * 2048);
      gload_lds16(bB + j * 32768 + kt, bD + j * 2048);
    }
    __syncthreads();
#pragma unroll
    for (int ks = 0; ks < 2; ++ks) {
      const int kb = (ks * 64 + lg * 16) ^ rdswz;
      s16x8 af[4], bf[4];
#pragma unroll
      for (int mf = 0; mf < 4; ++mf)
        af[mf] = *(const s16x8*)((const char*)As + (wm * 64 + mf * 16 + lr) * 128 + kb);
#pragma unroll
      for (int nf = 0; nf < 4; ++nf)
        bf[nf] = *(const s16x8*)((const char*)Bs + (wn * 64 + nf * 16 + lr) * 128 + kb);
#pragma unroll
      for (int mf = 0; mf < 4; ++mf)
#pragma unroll
        for (int nf = 0; nf < 4; ++nf)
          acc[mf][nf] = __builtin_amdgcn_mfma_f32_16x16x32_bf16(af[mf], bf[nf], acc[mf][nf], 0, 0, 0);
    }
  }

  // C/D layout: row = (l>>4)*4 + reg, col = l&15
  if (MODE == 1) {
    const int gn = nt * 128 + wn * 64;
    const int gm = m0 + wm * 64;
#pragma unroll
    for (int mf = 0; mf < 4; ++mf)
#pragma unroll
      for (int r = 0; r < 4; ++r) {
        int row = gm + mf * 16 + lg * 4 + r;
        float* C = (float*)Cptr + (size_t)row * ldc + gn;
#pragma unroll
        for (int nf = 0; nf < 4; ++nf) C[nf * 16 + lr] = acc[mf][nf][r];
      }
  } else {
    // MODE 2: RMS over the wave's 64-col head block, write to [32][2048][64]
    const int tz = nt >> 3;                       // 0=q 1=k 2=v
    const int h  = ((nt & 7) << 1) | wn;
    const int gm = m0 + wm * 64;
    unsigned short* base = tz == 0 ? qn : tz == 1 ? kn : vb;
    const float cmul = (tz == 0) ? 0.18033688f : 1.0f;   // 0.125 * log2(e)
#pragma unroll
    for (int mf = 0; mf < 4; ++mf)
#pragma unroll
      for (int r = 0; r < 4; ++r) {
        int m = gm + mf * 16 + lg * 4 + r;
        float ss = 0.f;
#pragma unroll
        for (int nf = 0; nf < 4; ++nf) ss += acc[mf][nf][r] * acc[mf][nf][r];
        ss += __shfl_xor(ss, 1);
        ss += __shfl_xor(ss, 2);
        ss += __shfl_xor(ss, 4);
        ss += __shfl_xor(ss, 8);
        float scale = (tz == 2) ? 1.0f : rsqrtf(ss * (1.0f / 64.0f) + 1e-6f) * cmul;
        int b = m >> 11, s = m & 2047;
        unsigned short* dst = base + ((size_t)(((b << 4) + h) * 2048 + s)) * 64;
#pragma unroll
        for (int nf = 0; nf < 4; ++nf)
          dst[nf * 16 + lr] = f2bf(acc[mf][nf][r] * scale);
      }
  }
}

// ---------------- flash attention (causal), split-K, uniform blocks ----------------
// R12-exact step machinery + P-store (f2bf — cvt_pk asm is BANNED: 2/2
// nondeterministic failures R11/R13). Sole R14 delta vs R12: T1 XCD remap —
// a pure bijective permutation of block ids (disjoint writes, no inter-block
// communication), so it cannot change any computed value.
__global__ __launch_bounds__(128, 2)
void k_attn(const unsigned short* __restrict__ Q,   // [32][2048][64], pre-scaled
            const unsigned short* __restrict__ K,
            const unsigned short* __restrict__ V,
            unsigned short* __restrict__ O,         // [2][2048][1024]
            unsigned short* __restrict__ pO,        // [32*16][2][64][64] bf16
            float* __restrict__ pL) {               // [32*16][2][64]
  __shared__ unsigned short Ks[2][64 * 64];     // [kv][dh] swizzled, 8KB each
  __shared__ unsigned short Vt[2][64 * 64];     // [dh][kv'] swizzled, 8KB each
  __shared__ unsigned short Ps[2][32 * 64];     // per-wave P [row][kv'] swizzled, 4KB

  const int id = blockIdx.x;
  // T1: id -> (xcd, j); bh = xcd + 8*(j&3), c = j>>2. Bijective: (id&7, bits3-4,
  // bits5-9) <-> (bh, c). Groups all 32 chunks of a bh onto one XCD under
  // round-robin bid->XCD dispatch (pure locality heuristic).
  const int xcd = id & 7, jj = id >> 3;
  const int bh = xcd + 8 * (jj & 3);
  const int c  = jj >> 2;
  const int p  = c >> 1, half = c & 1;
  const int tid = threadIdx.x;
  const int w = tid >> 6, l = tid & 63;
  const int lr = l & 15, lg = l >> 4;
  const int b = bh >> 4, h = bh & 15;

  const unsigned short* Kb = K + (size_t)bh * 2048 * 64;
  const unsigned short* Vb = V + (size_t)bh * 2048 * 64;
  const unsigned short* Qh = Q + (size_t)bh * 2048 * 64;

  const int ksub = l >> 3;                      // row-within-8 for K staging
  const int kskb = ((l & 7) ^ ksub) * 8;        // pre-swizzled 16B slot (elements)
  const int vc = tid & 31;                      // u32 column (kv' pair index)
  const int vg = tid >> 5;                      // 0..3 dh quarter
  const int kvlo = (vc & 15) + (vc >> 4) * 32;  // kv rows kvlo, kvlo+16
  const int rdswz = (lr & 7) << 4;
  const float FMAX = 11.5415603f;               // 8 * log2(e)

  const int NS = half ? 16 : 17;                // steps for this chunk
  int tile = half ? (31 - p) : p;
  int qw = tile * 64 + w * 32;

  s16x8 aq[2][2];
#pragma unroll
  for (int mf = 0; mf < 2; ++mf)
#pragma unroll
    for (int ks = 0; ks < 2; ++ks)
      aq[mf][ks] = *(const s16x8*)(Qh + (size_t)(qw + mf * 16 + lr) * 64 + ks * 32 + lg * 8);

  fx4 oacc[2][4] = {};
  float lsum[2][4] = {{0.f, 0.f, 0.f, 0.f}, {0.f, 0.f, 0.f, 0.f}};

  int kvt = half ? (16 - p) : 0;                // first KV tile index

  ux4 va0, va1, va2, va3;
  // prologue: stage KV tile kvt into buffer 0
#pragma unroll
  for (int j = 0; j < 4; ++j)
    gload_lds16(Kb + (size_t)(kvt * 64 + j * 16 + w * 8 + ksub) * 64 + kskb,
                &Ks[0][(j * 16 + w * 8) * 64]);
  va0 = *(const ux4*)(Vb + (size_t)(kvt * 64 + kvlo) * 64 + vg * 16);
  va1 = *(const ux4*)(Vb + (size_t)(kvt * 64 + kvlo) * 64 + vg * 16 + 8);
  va2 = *(const ux4*)(Vb + (size_t)(kvt * 64 + kvlo + 16) * 64 + vg * 16);
  va3 = *(const ux4*)(Vb + (size_t)(kvt * 64 + kvlo + 16) * 64 + vg * 16 + 8);
  {
    union { ux4 v; unsigned short u[8]; } a0, a1, a2, a3;
    a0.v = va0; a1.v = va1; a2.v = va2; a3.v = va3;
#pragma unroll
    for (int i = 0; i < 8; ++i) {
      int dh = vg * 16 + i;
      *(unsigned*)((char*)&Vt[0][0] + dh * 128 + ((vc * 4) ^ ((i & 7) << 4))) =
          (unsigned)a0.u[i] | ((unsigned)a2.u[i] << 16);
      *(unsigned*)((char*)&Vt[0][0] + (dh + 8) * 128 + ((vc * 4) ^ ((i & 7) << 4))) =
          (unsigned)a1.u[i] | ((unsigned)a3.u[i] << 16);
    }
  }
  __syncthreads();

#pragma unroll 1
  for (int s = 0; s < NS; ++s) {
    // chunk A: switch from tile p to tile 31-p after tile p's diagonal
    if (!half && s == p + 1) {
      // direct epilogue for tile p (complete causal range covered)
#pragma unroll
      for (int mf = 0; mf < 2; ++mf)
#pragma unroll
        for (int r = 0; r < 4; ++r) {
          float ssum = lsum[mf][r];
          ssum += __shfl_xor(ssum, 1);
          ssum += __shfl_xor(ssum, 2);
          ssum += __shfl_xor(ssum, 4);
          ssum += __shfl_xor(ssum, 8);
          float inv = 1.0f / ssum;
          int gq = qw + mf * 16 + lg * 4 + r;
          unsigned short* orow = O + ((size_t)(b * 2048 + gq)) * 1024 + h * 64;
#pragma unroll
          for (int nf = 0; nf < 4; ++nf)
            orow[nf * 16 + lr] = f2bf(oacc[mf][nf][r] * inv);
        }
      // reset accumulators AFTER all 8 (mf,r) outputs are written (R5 lesson)
#pragma unroll
      for (int mf = 0; mf < 2; ++mf) {
#pragma unroll
        for (int nf = 0; nf < 4; ++nf) oacc[mf][nf] = fx4{0.f, 0.f, 0.f, 0.f};
#pragma unroll
        for (int r = 0; r < 4; ++r) lsum[mf][r] = 0.f;
      }
      tile = 31 - p;
      qw = tile * 64 + w * 32;
#pragma unroll
      for (int mf = 0; mf < 2; ++mf)
#pragma unroll
        for (int ks = 0; ks < 2; ++ks)
          aq[mf][ks] = *(const s16x8*)(Qh + (size_t)(qw + mf * 16 + lr) * 64 + ks * 32 + lg * 8);
    }
    const int cur = s & 1;
    const int kv0 = kvt * 64;
    const bool pre = (s + 1 < NS);
    int nkvt = kvt + 1;
    if (!half && s == p) nkvt = 0;              // jump to tile 31-p's KV start
    if (pre) {
      const int kvn = nkvt * 64;
#pragma unroll
      for (int j = 0; j < 4; ++j)
        gload_lds16(Kb + (size_t)(kvn + j * 16 + w * 8 + ksub) * 64 + kskb,
                    &Ks[cur ^ 1][(j * 16 + w * 8) * 64]);
      va0 = *(const ux4*)(Vb + (size_t)(kvn + kvlo) * 64 + vg * 16);
      va1 = *(const ux4*)(Vb + (size_t)(kvn + kvlo) * 64 + vg * 16 + 8);
      va2 = *(const ux4*)(Vb + (size_t)(kvn + kvlo + 16) * 64 + vg * 16);
      va3 = *(const ux4*)(Vb + (size_t)(kvn + kvlo + 16) * 64 + vg * 16 + 8);
    }
    // QK^T
    fx4 sc[2][4] = {};
    __builtin_amdgcn_s_setprio(1);
#pragma unroll
    for (int ks = 0; ks < 2; ++ks) {
      const int kb = (ks * 64 + lg * 16) ^ rdswz;
#pragma unroll
      for (int nf = 0; nf < 4; ++nf) {
        s16x8 bk = *(const s16x8*)((const char*)&Ks[cur][0] + (nf * 16 + lr) * 128 + kb);
#pragma unroll
        for (int mf = 0; mf < 2; ++mf)
          sc[mf][nf] = __builtin_amdgcn_mfma_f32_16x16x32_bf16(aq[mf][ks], bk, sc[mf][nf], 0, 0, 0);
      }
    }
    __builtin_amdgcn_s_setprio(0);
    const bool diag = half ? (s == 15) : (s == p);
    if (diag) {                                 // diagonal tile: causal mask
#pragma unroll
      for (int mf = 0; mf < 2; ++mf)
#pragma unroll
        for (int nf = 0; nf < 4; ++nf)
#pragma unroll
          for (int r = 0; r < 4; ++r) {
            int gq = qw + mf * 16 + lg * 4 + r;
            int gk = kv0 + nf * 16 + lr;
            if (gk > gq) sc[mf][nf][r] = -3.0e38f;
          }
    }
    // softmax, fixed max; P -> LDS as paired u32 (kv' layout), swizzled
    char* pw = (char*)&Ps[w][0];
#pragma unroll
    for (int mf = 0; mf < 2; ++mf)
#pragma unroll
      for (int r = 0; r < 4; ++r) {
        float p0 = __builtin_amdgcn_exp2f(sc[mf][0][r] - FMAX);
        float p1 = __builtin_amdgcn_exp2f(sc[mf][1][r] - FMAX);
        float p2 = __builtin_amdgcn_exp2f(sc[mf][2][r] - FMAX);
        float p3 = __builtin_amdgcn_exp2f(sc[mf][3][r] - FMAX);
        lsum[mf][r] += (p0 + p1) + (p2 + p3);
        int row = mf * 16 + lg * 4 + r;
        char* pb = pw + row * 128;
        int swz = (row & 7) << 4;
        *(unsigned*)(pb + ((4 * lr) ^ swz))      = (unsigned)f2bf(p0) | ((unsigned)f2bf(p1) << 16);
        *(unsigned*)(pb + ((64 + 4 * lr) ^ swz)) = (unsigned)f2bf(p2) | ((unsigned)f2bf(p3) << 16);
      }
    // PV (A = P rows mf*16+lr over kv', B = Vt rows dh over kv')
    __builtin_amdgcn_s_setprio(1);
#pragma unroll
    for (int ks = 0; ks < 2; ++ks) {
      s16x8 pa[2], bv[4];
#pragma unroll
      for (int mf = 0; mf < 2; ++mf) {
        int row = mf * 16 + lr;
        pa[mf] = *(const s16x8*)(pw + row * 128 + ((ks * 64 + lg * 16) ^ ((row & 7) << 4)));
      }
#pragma unroll
      for (int nf = 0; nf < 4; ++nf) {
        int row = nf * 16 + lr;
        bv[nf] = *(const s16x8*)((const char*)&Vt[cur][0] + row * 128 +
                                 ((ks * 64 + lg * 16) ^ ((row & 7) << 4)));
      }
#pragma unroll
      for (int mf = 0; mf < 2; ++mf)
#pragma unroll
        for (int nf = 0; nf < 4; ++nf)
          oacc[mf][nf] = __builtin_amdgcn_mfma_f32_16x16x32_bf16(pa[mf], bv[nf], oacc[mf][nf], 0, 0, 0);
    }
    __builtin_amdgcn_s_setprio(0);
    if (pre) {                                  // late write of next V tile
      union { ux4 v; unsigned short u[8]; } a0, a1, a2, a3;
      a0.v = va0; a1.v = va1; a2.v = va2; a3.v = va3;
#pragma unroll
      for (int i = 0; i < 8; ++i) {
        int dh = vg * 16 + i;
        *(unsigned*)((char*)&Vt[cur ^ 1][0] + dh * 128 + ((vc * 4) ^ ((i & 7) << 4))) =
            (unsigned)a0.u[i] | ((unsigned)a2.u[i] << 16);
        *(unsigned*)((char*)&Vt[cur ^ 1][0] + (dh + 8) * 128 + ((vc * 4) ^ ((i & 7) << 4))) =
            (unsigned)a1.u[i] | ((unsigned)a3.u[i] << 16);
      }
    }
    kvt = nkvt;
    __syncthreads();
  }

  // final epilogue: write bf16 partials for tile 31-p
  const int slot = ((bh * 16 + p) * 2 + half);
#pragma unroll
  for (int mf = 0; mf < 2; ++mf)
#pragma unroll
    for (int r = 0; r < 4; ++r) {
      float ssum = lsum[mf][r];
      ssum += __shfl_xor(ssum, 1);
      ssum += __shfl_xor(ssum, 2);
      ssum += __shfl_xor(ssum, 4);
      ssum += __shfl_xor(ssum, 8);
      int row = w * 32 + mf * 16 + lg * 4 + r;  // 0..63 within tile
      unsigned short* po = pO + ((size_t)slot * 64 + row) * 64;
#pragma unroll
      for (int nf = 0; nf < 4; ++nf) po[nf * 16 + lr] = f2bf(oacc[mf][nf][r]);
      if (lr == 0) pL[slot * 64 + row] = ssum;
    }
}

// ---------------- merge split-K partials for tiles 16..31 (bf16 partials) ----------
__global__ __launch_bounds__(256)
void k_merge(const unsigned short* __restrict__ pO, const float* __restrict__ pL,
             unsigned short* __restrict__ O) {
  int gid = blockIdx.x * 256 + threadIdx.x;     // 524288 = 32768 rows x 16 quads
  int row = gid >> 4;                           // (bh*16 + p)*64 + r
  int quad = gid & 15;
  int slot = row >> 6;                          // bh*16 + p
  int r = row & 63;
  int bh = slot >> 4, p = slot & 15;
  const unsigned short* pa = pO + ((size_t)(slot * 2) * 64 + r) * 64 + quad * 4;
  const unsigned short* pb = pO + ((size_t)(slot * 2 + 1) * 64 + r) * 64 + quad * 4;
  ux2 ua = *(const ux2*)pa;
  ux2 ub = *(const ux2*)pb;
  float inv = 1.0f / (pL[(slot * 2) * 64 + r] + pL[(slot * 2 + 1) * 64 + r]);
  int tile = 31 - p;
  int b = bh >> 4, h = bh & 15;
  int s = tile * 64 + r;
  unsigned short* o = O + ((size_t)(b * 2048 + s)) * 1024 + h * 64 + quad * 4;
  float v0 = (bf2f((unsigned short)(ua[0] & 0xffff)) + bf2f((unsigned short)(ub[0] & 0xffff))) * inv;
  float v1 = (bf2f((unsigned short)(ua[0] >> 16))   + bf2f((unsigned short)(ub[0] >> 16)))   * inv;
  float v2 = (bf2f((unsigned short)(ua[1] & 0xffff)) + bf2f((unsigned short)(ub[1] & 0xffff))) * inv;
  float v3 = (bf2f((unsigned short)(ua[1] >> 16))   + bf2f((unsigned short)(ub[1] >> 16)))   * inv;
  ux2 out;
  out[0] = (unsigned)f2bf(v0) | ((unsigned)f2bf(v1) << 16);
  out[1] = (unsigned)f2bf(v2) | ((unsigned)f2bf(v3) << 16);
  *(ux2*)o = out;
}

// ---------------- launch ----------------
extern "C" void kernel_launch(void* const* d_in, const int* in_sizes, int n_in,
                              void* d_out, int out_size, void* d_ws, size_t ws_size,
                              hipStream_t stream) {
  const float* x  = (const float*)d_in[0];
  const float* Wq = (const float*)d_in[1];
  const float* Wk = (const float*)d_in[2];
  const float* Wv = (const float*)d_in[3];
  const float* Wo = (const float*)d_in[4];
  // d_in[5] = causal mask (tril) — implemented analytically.

  char* ws = (char*)d_ws;                                  // ~57 MB
  unsigned short* xb   = (unsigned short*)(ws);            // 8 MB  [4096][1024]
  unsigned short* WqT  = (unsigned short*)(ws + (8ll  << 20));
  unsigned short* WkT  = (unsigned short*)(ws + (10ll << 20));
  unsigned short* WvT  = (unsigned short*)(ws + (12ll << 20));
  unsigned short* WoT  = (unsigned short*)(ws + (14ll << 20));
  unsigned short* qn   = (unsigned short*)(ws + (16ll << 20)); // 8 MB [32][2048][64]
  unsigned short* kn   = (unsigned short*)(ws + (24ll << 20));
  unsigned short* vb   = (unsigned short*)(ws + (32ll << 20));
  unsigned short* attn = (unsigned short*)(ws + (40ll << 20)); // 8 MB [4096][1024]
  unsigned short* pO   = (unsigned short*)(ws + (48ll << 20)); // 8 MB bf16 partials
  float* pL            = (float*)(ws + (56ll << 20));          // 256 KB

  k_prep<<<8192, 256, 0, stream>>>(x, xb, Wq, Wk, Wv, Wo, WqT, WkT, WvT, WoT);
  k_gemm_bt<2><<<dim3(32, 24), 256, 0, stream>>>(xb, WqT, WkT, WvT, nullptr, 0, qn, kn, vb);
  k_attn<<<1024, 128, 0, stream>>>(qn, kn, vb, attn, pO, pL);
  k_merge<<<2048, 256, 0, stream>>>(pO, pL, attn);
  k_gemm_bt<1><<<dim3(32, 8), 256, 0, stream>>>(attn, WoT, WoT, WoT, d_out, 1024, nullptr, nullptr, nullptr);
}

// Round 15
// 100.904 us; speedup vs baseline: 1.3710x; 1.0306x over previous
//
#include <hip/hip_runtime.h>
#include <stdint.h>

// Problem constants: B=2, S=2048, D=1024, H=16, DH=64; M = B*S = 4096.

typedef __attribute__((ext_vector_type(8))) short s16x8;   // 8 bf16 (MFMA A/B frag)
typedef __attribute__((ext_vector_type(4))) float fx4;     // MFMA C/D frag
typedef __attribute__((ext_vector_type(4))) unsigned int ux4;
typedef __attribute__((ext_vector_type(2))) unsigned int ux2;

__device__ __forceinline__ unsigned short f2bf(float x) {
  unsigned u = __builtin_bit_cast(unsigned, x);
  u += 0x7fffu + ((u >> 16) & 1u);          // RNE
  return (unsigned short)(u >> 16);
}
__device__ __forceinline__ float bf2f(unsigned short h) {
  return __builtin_bit_cast(float, (unsigned)h << 16);
}

// async global->LDS, 16B per lane; LDS dest = wave-uniform base + lane*16
__device__ __forceinline__ void gload_lds16(const void* g, void* l) {
  __builtin_amdgcn_global_load_lds(
      (const __attribute__((address_space(1))) unsigned int*)g,
      (__attribute__((address_space(3))) unsigned int*)l, 16, 0, 0);
}

// ---------------- fused prep: x f32->bf16 + 4x weight transpose ----------------
// blocks 0..4095: conv, one fx4/thread -> 4096*256 = 1,048,576 quads = ALL of x.
// blocks 4096..8191: 32x32 transpose tiles for the 4 weights.
__global__ void k_prep(const float* __restrict__ X, unsigned short* __restrict__ Y,
                       const float* __restrict__ W0, const float* __restrict__ W1,
                       const float* __restrict__ W2, const float* __restrict__ W3,
                       unsigned short* __restrict__ T0, unsigned short* __restrict__ T1,
                       unsigned short* __restrict__ T2, unsigned short* __restrict__ T3) {
  __shared__ float t[32][33];
  int bid = blockIdx.x;
  int tid = threadIdx.x;
  if (bid < 4096) {
    int i = bid * 256 + tid;                    // exact cover of 1,048,576 quads
    fx4 v = *(const fx4*)(X + (size_t)i * 4);
    ux2 o;
    o[0] = (unsigned)f2bf(v[0]) | ((unsigned)f2bf(v[1]) << 16);
    o[1] = (unsigned)f2bf(v[2]) | ((unsigned)f2bf(v[3]) << 16);
    *(ux2*)(Y + (size_t)i * 4) = o;
    return;
  }
  int r = bid - 4096;
  int z = r >> 10;
  int rem = r & 1023;
  const float* W = z == 0 ? W0 : z == 1 ? W1 : z == 2 ? W2 : W3;
  unsigned short* T = z == 0 ? T0 : z == 1 ? T1 : z == 2 ? T2 : T3;
  int bx = (rem & 31) * 32, by = (rem >> 5) * 32;
  int tx = tid & 31, ty = tid >> 5;             // (32,8)
#pragma unroll
  for (int i = 0; i < 32; i += 8)
    t[ty + i][tx] = W[(size_t)(by + ty + i) * 1024 + bx + tx];
  __syncthreads();
#pragma unroll
  for (int i = 0; i < 32; i += 8)
    T[(size_t)(bx + ty + i) * 1024 + by + tx] = f2bf(t[tx][ty + i]);
}

// ---------------- GEMM: C[M x Ntot] = A[M x 1024] * Wt ----
// tile 128x128, BK=64, 256 thr (4 waves 2x2 of 64x64), mfma 16x16x32 bf16.
// launch_bounds(256,3): cap VGPR ~170 so 3 blocks/CU co-reside.
// MODE 1: f32 C store. MODE 2: fused RMSNorm-over-64 + split to qn/kn/vb.
template <int MODE>
__global__ __launch_bounds__(256, 3)
void k_gemm_bt(const unsigned short* __restrict__ A,
               const unsigned short* __restrict__ W0,
               const unsigned short* __restrict__ W1,
               const unsigned short* __restrict__ W2,
               void* __restrict__ Cptr, int ldc,
               unsigned short* __restrict__ qn, unsigned short* __restrict__ kn,
               unsigned short* __restrict__ vb) {
  __shared__ unsigned short As[128 * 64];
  __shared__ unsigned short Bs[128 * 64];
  const int tid = threadIdx.x;
  const int w = tid >> 6, l = tid & 63;
  const int lr = l & 15, lg = l >> 4;
  const int wm = w >> 1, wn = w & 1;
  const int m0 = blockIdx.x * 128;
  const int nt = blockIdx.y;
  const unsigned short* Bt = (nt < 8) ? W0 : (nt < 16) ? W1 : W2;
  const int n0 = (nt & 7) * 128;

  fx4 acc[4][4] = {};

  const int srow = w * 8 + (l >> 3);              // row within a 32-row issue block
  const int skb  = ((l & 7) ^ (l >> 3)) * 8;      // pre-swizzled 16B slot (elements)
  const unsigned short* aB = A  + (size_t)(m0 + srow) * 1024 + skb;
  const unsigned short* bB = Bt + (size_t)(n0 + srow) * 1024 + skb;
  unsigned short* aD = &As[w * 512];
  unsigned short* bD = &Bs[w * 512];
  const int rdswz = (l & 7) << 4;

  for (int kt = 0; kt < 1024; kt += 64) {
    __syncthreads();
#pragma unroll
    for (int j = 0; j < 4; ++j) {
      gload_lds16(aB + j * 32768 + kt, aD + j * 2048);
      gload_lds16(bB + j * 32768 + kt, bD + j * 2048);
    }
    __syncthreads();
#pragma unroll
    for (int ks = 0; ks < 2; ++ks) {
      const int kb = (ks * 64 + lg * 16) ^ rdswz;
      s16x8 af[4], bf[4];
#pragma unroll
      for (int mf = 0; mf < 4; ++mf)
        af[mf] = *(const s16x8*)((const char*)As + (wm * 64 + mf * 16 + lr) * 128 + kb);
#pragma unroll
      for (int nf = 0; nf < 4; ++nf)
        bf[nf] = *(const s16x8*)((const char*)Bs + (wn * 64 + nf * 16 + lr) * 128 + kb);
#pragma unroll
      for (int mf = 0; mf < 4; ++mf)
#pragma unroll
        for (int nf = 0; nf < 4; ++nf)
          acc[mf][nf] = __builtin_amdgcn_mfma_f32_16x16x32_bf16(af[mf], bf[nf], acc[mf][nf], 0, 0, 0);
    }
  }

  // C/D layout: row = (l>>4)*4 + reg, col = l&15
  if (MODE == 1) {
    const int gn = nt * 128 + wn * 64;
    const int gm = m0 + wm * 64;
#pragma unroll
    for (int mf = 0; mf < 4; ++mf)
#pragma unroll
      for (int r = 0; r < 4; ++r) {
        int row = gm + mf * 16 + lg * 4 + r;
        float* C = (float*)Cptr + (size_t)row * ldc + gn;
#pragma unroll
        for (int nf = 0; nf < 4; ++nf) C[nf * 16 + lr] = acc[mf][nf][r];
      }
  } else {
    // MODE 2: RMS over the wave's 64-col head block, write to [32][2048][64]
    const int tz = nt >> 3;                       // 0=q 1=k 2=v
    const int h  = ((nt & 7) << 1) | wn;
    const int gm = m0 + wm * 64;
    unsigned short* base = tz == 0 ? qn : tz == 1 ? kn : vb;
    const float cmul = (tz == 0) ? 0.18033688f : 1.0f;   // 0.125 * log2(e)
#pragma unroll
    for (int mf = 0; mf < 4; ++mf)
#pragma unroll
      for (int r = 0; r < 4; ++r) {
        int m = gm + mf * 16 + lg * 4 + r;
        float ss = 0.f;
#pragma unroll
        for (int nf = 0; nf < 4; ++nf) ss += acc[mf][nf][r] * acc[mf][nf][r];
        ss += __shfl_xor(ss, 1);
        ss += __shfl_xor(ss, 2);
        ss += __shfl_xor(ss, 4);
        ss += __shfl_xor(ss, 8);
        float scale = (tz == 2) ? 1.0f : rsqrtf(ss * (1.0f / 64.0f) + 1e-6f) * cmul;
        int b = m >> 11, s = m & 2047;
        unsigned short* dst = base + ((size_t)(((b << 4) + h) * 2048 + s)) * 64;
#pragma unroll
        for (int nf = 0; nf < 4; ++nf)
          dst[nf * 16 + lr] = f2bf(acc[mf][nf][r] * scale);
      }
  }
}

// ---------------- out-proj GEMM: C[4096 x 1024] f32 = attn * WoT ----
// 64x128 tile, BK=64, 256 thr (4 waves 2x2: wave = 32m x 64n), 24KB LDS ->
// 512 blocks = 2 blocks/CU (8 waves/CU) vs old 128x128's 1 block/CU (R14
// diagnosis: out-proj latency-starved at 1 wave/SIMD). Same staging/swizzle/
// C-layout skeleton as k_gemm_bt (verified); acc 2x4, ~85 VGPR.
__global__ __launch_bounds__(256, 2)
void k_gemm_o(const unsigned short* __restrict__ A,
              const unsigned short* __restrict__ Bt,
              float* __restrict__ C) {
  __shared__ unsigned short As[64 * 64];        // 8KB
  __shared__ unsigned short Bs[128 * 64];       // 16KB
  const int tid = threadIdx.x;
  const int w = tid >> 6, l = tid & 63;
  const int lr = l & 15, lg = l >> 4;
  const int wm = w >> 1, wn = w & 1;
  const int m0 = blockIdx.x * 64;
  const int n0 = blockIdx.y * 128;

  fx4 acc[2][4] = {};

  const int srow = w * 8 + (l >> 3);              // rows w*8 .. w*8+7
  const int skb  = ((l & 7) ^ (l >> 3)) * 8;      // pre-swizzled 16B slot (elements)
  const unsigned short* aB = A  + (size_t)(m0 + srow) * 1024 + skb;
  const unsigned short* bB = Bt + (size_t)(n0 + srow) * 1024 + skb;
  unsigned short* aD = &As[w * 512];
  unsigned short* bD = &Bs[w * 512];
  const int rdswz = (l & 7) << 4;

  for (int kt = 0; kt < 1024; kt += 64) {
    __syncthreads();
    gload_lds16(aB + kt, aD);                     // A rows 0-31
    gload_lds16(aB + 32768 + kt, aD + 2048);      // A rows 32-63
#pragma unroll
    for (int j = 0; j < 4; ++j)                   // B rows 0-127
      gload_lds16(bB + j * 32768 + kt, bD + j * 2048);
    __syncthreads();
#pragma unroll
    for (int ks = 0; ks < 2; ++ks) {
      const int kb = (ks * 64 + lg * 16) ^ rdswz;
      s16x8 af[2], bf[4];
#pragma unroll
      for (int mf = 0; mf < 2; ++mf)
        af[mf] = *(const s16x8*)((const char*)As + (wm * 32 + mf * 16 + lr) * 128 + kb);
#pragma unroll
      for (int nf = 0; nf < 4; ++nf)
        bf[nf] = *(const s16x8*)((const char*)Bs + (wn * 64 + nf * 16 + lr) * 128 + kb);
#pragma unroll
      for (int mf = 0; mf < 2; ++mf)
#pragma unroll
        for (int nf = 0; nf < 4; ++nf)
          acc[mf][nf] = __builtin_amdgcn_mfma_f32_16x16x32_bf16(af[mf], bf[nf], acc[mf][nf], 0, 0, 0);
    }
  }

  // C/D layout: row = lg*4 + r, col = lr (verified pattern)
  const int gn = n0 + wn * 64;
  const int gm = m0 + wm * 32;
#pragma unroll
  for (int mf = 0; mf < 2; ++mf)
#pragma unroll
    for (int r = 0; r < 4; ++r) {
      int row = gm + mf * 16 + lg * 4 + r;
      float* Cp = C + (size_t)row * 1024 + gn;
#pragma unroll
      for (int nf = 0; nf < 4; ++nf) Cp[nf * 16 + lr] = acc[mf][nf][r];
    }
}

// ---------------- flash attention (causal), split-K, uniform blocks ----------------
// R14-exact (green, replay-validated): R12 step machinery + T1 XCD remap.
// cvt_pk asm BANNED (2/2 nondeterministic failures R11/R13).
__global__ __launch_bounds__(128, 2)
void k_attn(const unsigned short* __restrict__ Q,   // [32][2048][64], pre-scaled
            const unsigned short* __restrict__ K,
            const unsigned short* __restrict__ V,
            unsigned short* __restrict__ O,         // [2][2048][1024]
            unsigned short* __restrict__ pO,        // [32*16][2][64][64] bf16
            float* __restrict__ pL) {               // [32*16][2][64]
  __shared__ unsigned short Ks[2][64 * 64];     // [kv][dh] swizzled, 8KB each
  __shared__ unsigned short Vt[2][64 * 64];     // [dh][kv'] swizzled, 8KB each
  __shared__ unsigned short Ps[2][32 * 64];     // per-wave P [row][kv'] swizzled, 4KB

  const int id = blockIdx.x;
  // T1: id -> (xcd, j); bh = xcd + 8*(j&3), c = j>>2. Bijective; groups all 32
  // chunks of a bh onto one XCD under round-robin dispatch (FETCH 114->12 MB, R14).
  const int xcd = id & 7, jj = id >> 3;
  const int bh = xcd + 8 * (jj & 3);
  const int c  = jj >> 2;
  const int p  = c >> 1, half = c & 1;
  const int tid = threadIdx.x;
  const int w = tid >> 6, l = tid & 63;
  const int lr = l & 15, lg = l >> 4;
  const int b = bh >> 4, h = bh & 15;

  const unsigned short* Kb = K + (size_t)bh * 2048 * 64;
  const unsigned short* Vb = V + (size_t)bh * 2048 * 64;
  const unsigned short* Qh = Q + (size_t)bh * 2048 * 64;

  const int ksub = l >> 3;                      // row-within-8 for K staging
  const int kskb = ((l & 7) ^ ksub) * 8;        // pre-swizzled 16B slot (elements)
  const int vc = tid & 31;                      // u32 column (kv' pair index)
  const int vg = tid >> 5;                      // 0..3 dh quarter
  const int kvlo = (vc & 15) + (vc >> 4) * 32;  // kv rows kvlo, kvlo+16
  const int rdswz = (lr & 7) << 4;
  const float FMAX = 11.5415603f;               // 8 * log2(e)

  const int NS = half ? 16 : 17;                // steps for this chunk
  int tile = half ? (31 - p) : p;
  int qw = tile * 64 + w * 32;

  s16x8 aq[2][2];
#pragma unroll
  for (int mf = 0; mf < 2; ++mf)
#pragma unroll
    for (int ks = 0; ks < 2; ++ks)
      aq[mf][ks] = *(const s16x8*)(Qh + (size_t)(qw + mf * 16 + lr) * 64 + ks * 32 + lg * 8);

  fx4 oacc[2][4] = {};
  float lsum[2][4] = {{0.f, 0.f, 0.f, 0.f}, {0.f, 0.f, 0.f, 0.f}};

  int kvt = half ? (16 - p) : 0;                // first KV tile index

  ux4 va0, va1, va2, va3;
  // prologue: stage KV tile kvt into buffer 0
#pragma unroll
  for (int j = 0; j < 4; ++j)
    gload_lds16(Kb + (size_t)(kvt * 64 + j * 16 + w * 8 + ksub) * 64 + kskb,
                &Ks[0][(j * 16 + w * 8) * 64]);
  va0 = *(const ux4*)(Vb + (size_t)(kvt * 64 + kvlo) * 64 + vg * 16);
  va1 = *(const ux4*)(Vb + (size_t)(kvt * 64 + kvlo) * 64 + vg * 16 + 8);
  va2 = *(const ux4*)(Vb + (size_t)(kvt * 64 + kvlo + 16) * 64 + vg * 16);
  va3 = *(const ux4*)(Vb + (size_t)(kvt * 64 + kvlo + 16) * 64 + vg * 16 + 8);
  {
    union { ux4 v; unsigned short u[8]; } a0, a1, a2, a3;
    a0.v = va0; a1.v = va1; a2.v = va2; a3.v = va3;
#pragma unroll
    for (int i = 0; i < 8; ++i) {
      int dh = vg * 16 + i;
      *(unsigned*)((char*)&Vt[0][0] + dh * 128 + ((vc * 4) ^ ((i & 7) << 4))) =
          (unsigned)a0.u[i] | ((unsigned)a2.u[i] << 16);
      *(unsigned*)((char*)&Vt[0][0] + (dh + 8) * 128 + ((vc * 4) ^ ((i & 7) << 4))) =
          (unsigned)a1.u[i] | ((unsigned)a3.u[i] << 16);
    }
  }
  __syncthreads();

#pragma unroll 1
  for (int s = 0; s < NS; ++s) {
    // chunk A: switch from tile p to tile 31-p after tile p's diagonal
    if (!half && s == p + 1) {
      // direct epilogue for tile p (complete causal range covered)
#pragma unroll
      for (int mf = 0; mf < 2; ++mf)
#pragma unroll
        for (int r = 0; r < 4; ++r) {
          float ssum = lsum[mf][r];
          ssum += __shfl_xor(ssum, 1);
          ssum += __shfl_xor(ssum, 2);
          ssum += __shfl_xor(ssum, 4);
          ssum += __shfl_xor(ssum, 8);
          float inv = 1.0f / ssum;
          int gq = qw + mf * 16 + lg * 4 + r;
          unsigned short* orow = O + ((size_t)(b * 2048 + gq)) * 1024 + h * 64;
#pragma unroll
          for (int nf = 0; nf < 4; ++nf)
            orow[nf * 16 + lr] = f2bf(oacc[mf][nf][r] * inv);
        }
      // reset accumulators AFTER all 8 (mf,r) outputs are written (R5 lesson)
#pragma unroll
      for (int mf = 0; mf < 2; ++mf) {
#pragma unroll
        for (int nf = 0; nf < 4; ++nf) oacc[mf][nf] = fx4{0.f, 0.f, 0.f, 0.f};
#pragma unroll
        for (int r = 0; r < 4; ++r) lsum[mf][r] = 0.f;
      }
      tile = 31 - p;
      qw = tile * 64 + w * 32;
#pragma unroll
      for (int mf = 0; mf < 2; ++mf)
#pragma unroll
        for (int ks = 0; ks < 2; ++ks)
          aq[mf][ks] = *(const s16x8*)(Qh + (size_t)(qw + mf * 16 + lr) * 64 + ks * 32 + lg * 8);
    }
    const int cur = s & 1;
    const int kv0 = kvt * 64;
    const bool pre = (s + 1 < NS);
    int nkvt = kvt + 1;
    if (!half && s == p) nkvt = 0;              // jump to tile 31-p's KV start
    if (pre) {
      const int kvn = nkvt * 64;
#pragma unroll
      for (int j = 0; j < 4; ++j)
        gload_lds16(Kb + (size_t)(kvn + j * 16 + w * 8 + ksub) * 64 + kskb,
                    &Ks[cur ^ 1][(j * 16 + w * 8) * 64]);
      va0 = *(const ux4*)(Vb + (size_t)(kvn + kvlo) * 64 + vg * 16);
      va1 = *(const ux4*)(Vb + (size_t)(kvn + kvlo) * 64 + vg * 16 + 8);
      va2 = *(const ux4*)(Vb + (size_t)(kvn + kvlo + 16) * 64 + vg * 16);
      va3 = *(const ux4*)(Vb + (size_t)(kvn + kvlo + 16) * 64 + vg * 16 + 8);
    }
    // QK^T
    fx4 sc[2][4] = {};
    __builtin_amdgcn_s_setprio(1);
#pragma unroll
    for (int ks = 0; ks < 2; ++ks) {
      const int kb = (ks * 64 + lg * 16) ^ rdswz;
#pragma unroll
      for (int nf = 0; nf < 4; ++nf) {
        s16x8 bk = *(const s16x8*)((const char*)&Ks[cur][0] + (nf * 16 + lr) * 128 + kb);
#pragma unroll
        for (int mf = 0; mf < 2; ++mf)
          sc[mf][nf] = __builtin_amdgcn_mfma_f32_16x16x32_bf16(aq[mf][ks], bk, sc[mf][nf], 0, 0, 0);
      }
    }
    __builtin_amdgcn_s_setprio(0);
    const bool diag = half ? (s == 15) : (s == p);
    if (diag) {                                 // diagonal tile: causal mask
#pragma unroll
      for (int mf = 0; mf < 2; ++mf)
#pragma unroll
        for (int nf = 0; nf < 4; ++nf)
#pragma unroll
          for (int r = 0; r < 4; ++r) {
            int gq = qw + mf * 16 + lg * 4 + r;
            int gk = kv0 + nf * 16 + lr;
            if (gk > gq) sc[mf][nf][r] = -3.0e38f;
          }
    }
    // softmax, fixed max; P -> LDS as paired u32 (kv' layout), swizzled
    char* pw = (char*)&Ps[w][0];
#pragma unroll
    for (int mf = 0; mf < 2; ++mf)
#pragma unroll
      for (int r = 0; r < 4; ++r) {
        float p0 = __builtin_amdgcn_exp2f(sc[mf][0][r] - FMAX);
        float p1 = __builtin_amdgcn_exp2f(sc[mf][1][r] - FMAX);
        float p2 = __builtin_amdgcn_exp2f(sc[mf][2][r] - FMAX);
        float p3 = __builtin_amdgcn_exp2f(sc[mf][3][r] - FMAX);
        lsum[mf][r] += (p0 + p1) + (p2 + p3);
        int row = mf * 16 + lg * 4 + r;
        char* pb = pw + row * 128;
        int swz = (row & 7) << 4;
        *(unsigned*)(pb + ((4 * lr) ^ swz))      = (unsigned)f2bf(p0) | ((unsigned)f2bf(p1) << 16);
        *(unsigned*)(pb + ((64 + 4 * lr) ^ swz)) = (unsigned)f2bf(p2) | ((unsigned)f2bf(p3) << 16);
      }
    // PV (A = P rows mf*16+lr over kv', B = Vt rows dh over kv')
    __builtin_amdgcn_s_setprio(1);
#pragma unroll
    for (int ks = 0; ks < 2; ++ks) {
      s16x8 pa[2], bv[4];
#pragma unroll
      for (int mf = 0; mf < 2; ++mf) {
        int row = mf * 16 + lr;
        pa[mf] = *(const s16x8*)(pw + row * 128 + ((ks * 64 + lg * 16) ^ ((row & 7) << 4)));
      }
#pragma unroll
      for (int nf = 0; nf < 4; ++nf) {
        int row = nf * 16 + lr;
        bv[nf] = *(const s16x8*)((const char*)&Vt[cur][0] + row * 128 +
                                 ((ks * 64 + lg * 16) ^ ((row & 7) << 4)));
      }
#pragma unroll
      for (int mf = 0; mf < 2; ++mf)
#pragma unroll
        for (int nf = 0; nf < 4; ++nf)
          oacc[mf][nf] = __builtin_amdgcn_mfma_f32_16x16x32_bf16(pa[mf], bv[nf], oacc[mf][nf], 0, 0, 0);
    }
    __builtin_amdgcn_s_setprio(0);
    if (pre) {                                  // late write of next V tile
      union { ux4 v; unsigned short u[8]; } a0, a1, a2, a3;
      a0.v = va0; a1.v = va1; a2.v = va2; a3.v = va3;
#pragma unroll
      for (int i = 0; i < 8; ++i) {
        int dh = vg * 16 + i;
        *(unsigned*)((char*)&Vt[cur ^ 1][0] + dh * 128 + ((vc * 4) ^ ((i & 7) << 4))) =
            (unsigned)a0.u[i] | ((unsigned)a2.u[i] << 16);
        *(unsigned*)((char*)&Vt[cur ^ 1][0] + (dh + 8) * 128 + ((vc * 4) ^ ((i & 7) << 4))) =
            (unsigned)a1.u[i] | ((unsigned)a3.u[i] << 16);
      }
    }
    kvt = nkvt;
    __syncthreads();
  }

  // final epilogue: write bf16 partials for tile 31-p
  const int slot = ((bh * 16 + p) * 2 + half);
#pragma unroll
  for (int mf = 0; mf < 2; ++mf)
#pragma unroll
    for (int r = 0; r < 4; ++r) {
      float ssum = lsum[mf][r];
      ssum += __shfl_xor(ssum, 1);
      ssum += __shfl_xor(ssum, 2);
      ssum += __shfl_xor(ssum, 4);
      ssum += __shfl_xor(ssum, 8);
      int row = w * 32 + mf * 16 + lg * 4 + r;  // 0..63 within tile
      unsigned short* po = pO + ((size_t)slot * 64 + row) * 64;
#pragma unroll
      for (int nf = 0; nf < 4; ++nf) po[nf * 16 + lr] = f2bf(oacc[mf][nf][r]);
      if (lr == 0) pL[slot * 64 + row] = ssum;
    }
}

// ---------------- merge split-K partials for tiles 16..31 (bf16 partials) ----------
__global__ __launch_bounds__(256)
void k_merge(const unsigned short* __restrict__ pO, const float* __restrict__ pL,
             unsigned short* __restrict__ O) {
  int gid = blockIdx.x * 256 + threadIdx.x;     // 524288 = 32768 rows x 16 quads
  int row = gid >> 4;                           // (bh*16 + p)*64 + r
  int quad = gid & 15;
  int slot = row >> 6;                          // bh*16 + p
  int r = row & 63;
  int bh = slot >> 4, p = slot & 15;
  const unsigned short* pa = pO + ((size_t)(slot * 2) * 64 + r) * 64 + quad * 4;
  const unsigned short* pb = pO + ((size_t)(slot * 2 + 1) * 64 + r) * 64 + quad * 4;
  ux2 ua = *(const ux2*)pa;
  ux2 ub = *(const ux2*)pb;
  float inv = 1.0f / (pL[(slot * 2) * 64 + r] + pL[(slot * 2 + 1) * 64 + r]);
  int tile = 31 - p;
  int b = bh >> 4, h = bh & 15;
  int s = tile * 64 + r;
  unsigned short* o = O + ((size_t)(b * 2048 + s)) * 1024 + h * 64 + quad * 4;
  float v0 = (bf2f((unsigned short)(ua[0] & 0xffff)) + bf2f((unsigned short)(ub[0] & 0xffff))) * inv;
  float v1 = (bf2f((unsigned short)(ua[0] >> 16))   + bf2f((unsigned short)(ub[0] >> 16)))   * inv;
  float v2 = (bf2f((unsigned short)(ua[1] & 0xffff)) + bf2f((unsigned short)(ub[1] & 0xffff))) * inv;
  float v3 = (bf2f((unsigned short)(ua[1] >> 16))   + bf2f((unsigned short)(ub[1] >> 16)))   * inv;
  ux2 out;
  out[0] = (unsigned)f2bf(v0) | ((unsigned)f2bf(v1) << 16);
  out[1] = (unsigned)f2bf(v2) | ((unsigned)f2bf(v3) << 16);
  *(ux2*)o = out;
}

// ---------------- launch ----------------
extern "C" void kernel_launch(void* const* d_in, const int* in_sizes, int n_in,
                              void* d_out, int out_size, void* d_ws, size_t ws_size,
                              hipStream_t stream) {
  const float* x  = (const float*)d_in[0];
  const float* Wq = (const float*)d_in[1];
  const float* Wk = (const float*)d_in[2];
  const float* Wv = (const float*)d_in[3];
  const float* Wo = (const float*)d_in[4];
  // d_in[5] = causal mask (tril) — implemented analytically.

  char* ws = (char*)d_ws;                                  // ~57 MB
  unsigned short* xb   = (unsigned short*)(ws);            // 8 MB  [4096][1024]
  unsigned short* WqT  = (unsigned short*)(ws + (8ll  << 20));
  unsigned short* WkT  = (unsigned short*)(ws + (10ll << 20));
  unsigned short* WvT  = (unsigned short*)(ws + (12ll << 20));
  unsigned short* WoT  = (unsigned short*)(ws + (14ll << 20));
  unsigned short* qn   = (unsigned short*)(ws + (16ll << 20)); // 8 MB [32][2048][64]
  unsigned short* kn   = (unsigned short*)(ws + (24ll << 20));
  unsigned short* vb   = (unsigned short*)(ws + (32ll << 20));
  unsigned short* attn = (unsigned short*)(ws + (40ll << 20)); // 8 MB [4096][1024]
  unsigned short* pO   = (unsigned short*)(ws + (48ll << 20)); // 8 MB bf16 partials
  float* pL            = (float*)(ws + (56ll << 20));          // 256 KB

  k_prep<<<8192, 256, 0, stream>>>(x, xb, Wq, Wk, Wv, Wo, WqT, WkT, WvT, WoT);
  k_gemm_bt<2><<<dim3(32, 24), 256, 0, stream>>>(xb, WqT, WkT, WvT, nullptr, 0, qn, kn, vb);
  k_attn<<<1024, 128, 0, stream>>>(qn, kn, vb, attn, pO, pL);
  k_merge<<<2048, 256, 0, stream>>>(pO, pL, attn);
  k_gemm_o<<<dim3(64, 8), 256, 0, stream>>>(attn, WoT, (float*)d_out);
}